// Round 13
// baseline (2838.149 us; speedup 1.0000x reference)
//
#include <hip/hip_runtime.h>
#include <hip/hip_bf16.h>
#include <hip/hip_fp16.h>

typedef unsigned int u32;
typedef unsigned short u16;
typedef _Float16 f16x8 __attribute__((ext_vector_type(8)));
typedef float f32x4 __attribute__((ext_vector_type(4)));

#define NBLK1 512        // CSR blocks (edge chunks)
#define MMBLK 256        // mm blocks / mm1 side of csr_mega
#define GATE_MAGIC 0x13572468u

// ---------- fp16 pack/unpack ----------
__device__ __forceinline__ u16 f2h(float f) { return __half_as_ushort(__float2half(f)); }
__device__ __forceinline__ u32 packh2(float a, float b) {
    return (u32)f2h(a) | ((u32)f2h(b) << 16);
}
__device__ __forceinline__ __half2 sx(__half2 v, int m) {
    int iv = __shfl_xor(*(int*)&v, m, 64);
    return *(__half2*)&iv;
}

// ---------- int-width-agnostic index load (w64=1 -> int64 data on device) ----------
__device__ __forceinline__ int gidx(const void* p, long long i, int w64) {
    if (w64) return (int)((const long long*)p)[i];
    return ((const int*)p)[i];
}

// per-block int64 detection (probe odd words; int32 data -> some nonzero, int64 -> all zero)
__device__ __forceinline__ int detect_w64(const int* edge_words, int E, int tid, int* sh) {
    if (tid == 0) *sh = 0;
    __syncthreads();
    const long long totalWords = 2LL * E;
    const long long step = totalWords / 256;
    long long w = ((long long)tid * step) | 1;
    int nz = (w < totalWords) ? edge_words[w] : 0;
    if (nz) atomicOr(sh, 1);
    __syncthreads();
    return (*sh) ? 0 : 1;
}

// device-scope software barrier among `target` participating blocks (all co-resident)
__device__ __forceinline__ void gbar(u32* bar, u32 target) {
    __threadfence();
    __syncthreads();
    if (threadIdx.x == 0) {
        atomicAdd(bar, 1u);
        while (atomicAdd(bar, 0u) < target) __builtin_amdgcn_s_sleep(2);
    }
    __syncthreads();
    __threadfence();
}

// ---------- MFMA lift body (shared by mm1-in-mega and standalone mm) ----------
template <typename T>
__device__ __forceinline__ void mm_body(const T* __restrict__ X,
                                        const float* __restrict__ Wl,
                                        const float* __restrict__ Wr,
                                        const float* __restrict__ Bv,
                                        u16* __restrict__ Z, u16* __restrict__ R,
                                        int n, int waveId, int nwaves) {
    const int lane = threadIdx.x & 63;
    const int quad = lane >> 4;
    const int m16 = lane & 15;
    f16x8 bl[2][4], br[2][4];
#pragma unroll
    for (int kh = 0; kh < 2; ++kh)
#pragma unroll
        for (int t = 0; t < 4; ++t)
#pragma unroll
            for (int j = 0; j < 8; ++j) {
                int k = kh * 32 + quad * 8 + j;
                int c = t * 16 + m16;
                bl[kh][t][j] = (_Float16)Wl[k * 64 + c];
                br[kh][t][j] = (_Float16)Wr[k * 64 + c];
            }
    float bias_t[4];
#pragma unroll
    for (int t = 0; t < 4; ++t) bias_t[t] = Bv[t * 16 + m16];

    const int ntiles = (n + 15) >> 4;
    for (int tile = waveId; tile < ntiles; tile += nwaves) {
        const int nodeBase = tile << 4;
        int nodeA = nodeBase + m16;
        if (nodeA >= n) nodeA = n - 1;
        f16x8 a[2];
        if constexpr (sizeof(T) == 2) {
            const _Float16* xp = (const _Float16*)X + (size_t)nodeA * 64;
#pragma unroll
            for (int kh = 0; kh < 2; ++kh)
                a[kh] = *(const f16x8*)(xp + kh * 32 + quad * 8);
        } else {
#pragma unroll
            for (int kh = 0; kh < 2; ++kh) {
                const float4* p = (const float4*)((const float*)X + (size_t)nodeA * 64 + kh * 32 + quad * 8);
                float4 x0 = p[0], x1 = p[1];
                a[kh][0] = (_Float16)x0.x; a[kh][1] = (_Float16)x0.y;
                a[kh][2] = (_Float16)x0.z; a[kh][3] = (_Float16)x0.w;
                a[kh][4] = (_Float16)x1.x; a[kh][5] = (_Float16)x1.y;
                a[kh][6] = (_Float16)x1.z; a[kh][7] = (_Float16)x1.w;
            }
        }
        f32x4 cl[4], cr[4];
#pragma unroll
        for (int t = 0; t < 4; ++t) {
            f32x4 c0 = {0.f, 0.f, 0.f, 0.f};
            c0 = __builtin_amdgcn_mfma_f32_16x16x32_f16(a[0], bl[0][t], c0, 0, 0, 0);
            c0 = __builtin_amdgcn_mfma_f32_16x16x32_f16(a[1], bl[1][t], c0, 0, 0, 0);
            cl[t] = c0;
            f32x4 c1 = {0.f, 0.f, 0.f, 0.f};
            c1 = __builtin_amdgcn_mfma_f32_16x16x32_f16(a[0], br[0][t], c1, 0, 0, 0);
            c1 = __builtin_amdgcn_mfma_f32_16x16x32_f16(a[1], br[1][t], c1, 0, 0, 0);
            cr[t] = c1;
        }
#pragma unroll
        for (int rg = 0; rg < 4; ++rg) {
            const int node = nodeBase + quad * 4 + rg;
            if (node < n) {
#pragma unroll
                for (int t = 0; t < 4; ++t) {
                    const int c = t * 16 + m16;
                    Z[(size_t)node * 64 + c] = f2h(cl[t][rg]);
                    R[(size_t)node * 64 + c] = f2h(cr[t][rg] + bias_t[t]);
                }
            }
        }
    }
}

// ---------- agg body: relu(mean_neighbors(Z) + R); oct layout, uint4 gathers ----------
// oct==0 lanes return the node's packed H row chunk (uint4, ch sub*8..sub*8+7)
__device__ __forceinline__ uint4 agg_node(const u16* __restrict__ Zin,
                                          const u16* __restrict__ Rin,
                                          const u32* __restrict__ offs,
                                          const int* __restrict__ ss,
                                          int node, int lane, int oct, int sub) {
    const uint4* Z16 = (const uint4*)Zin;
    const int off = (int)offs[node], end = (int)offs[node + 1];
    const int deg = end - off;
    const __half2 zero2 = __float2half2_rn(0.f);
    const __half2 one2 = __float2half2_rn(1.f);
    __half2 a0 = zero2, a1 = zero2, a2 = zero2, a3 = zero2;
    __half2 b0 = zero2, b1 = zero2, b2 = zero2, b3 = zero2;
    for (int base = off; base < end; base += 64) {
        const int cnt = min(64, end - base);
        const int idx = ss[base + (lane < cnt ? lane : cnt - 1)];
        int p = 0;
        for (; p + 16 <= cnt; p += 16) {
            int s0 = __shfl(idx, p + oct, 64);
            int s1 = __shfl(idx, p + 8 + oct, 64);
            uint4 u0 = Z16[(size_t)s0 * 8 + sub];
            uint4 u1 = Z16[(size_t)s1 * 8 + sub];
            a0 = __hadd2(a0, *(const __half2*)&u0.x);
            a1 = __hadd2(a1, *(const __half2*)&u0.y);
            a2 = __hadd2(a2, *(const __half2*)&u0.z);
            a3 = __hadd2(a3, *(const __half2*)&u0.w);
            b0 = __hadd2(b0, *(const __half2*)&u1.x);
            b1 = __hadd2(b1, *(const __half2*)&u1.y);
            b2 = __hadd2(b2, *(const __half2*)&u1.z);
            b3 = __hadd2(b3, *(const __half2*)&u1.w);
        }
        const int rem = cnt - p;
        if (rem) {
            int j = p + oct;
            int s0 = __shfl(idx, j < cnt ? j : cnt - 1, 64);
            uint4 u0 = Z16[(size_t)s0 * 8 + sub];
            __half2 m0 = (j < cnt) ? one2 : zero2;
            a0 = __hfma2(*(const __half2*)&u0.x, m0, a0);
            a1 = __hfma2(*(const __half2*)&u0.y, m0, a1);
            a2 = __hfma2(*(const __half2*)&u0.z, m0, a2);
            a3 = __hfma2(*(const __half2*)&u0.w, m0, a3);
            if (rem > 8) {
                int j1 = p + 8 + oct;
                int s1 = __shfl(idx, j1 < cnt ? j1 : cnt - 1, 64);
                uint4 u1 = Z16[(size_t)s1 * 8 + sub];
                __half2 m1 = (j1 < cnt) ? one2 : zero2;
                b0 = __hfma2(*(const __half2*)&u1.x, m1, b0);
                b1 = __hfma2(*(const __half2*)&u1.y, m1, b1);
                b2 = __hfma2(*(const __half2*)&u1.z, m1, b2);
                b3 = __hfma2(*(const __half2*)&u1.w, m1, b3);
            }
        }
    }
    a0 = __hadd2(a0, b0); a1 = __hadd2(a1, b1);
    a2 = __hadd2(a2, b2); a3 = __hadd2(a3, b3);
    a0 = __hadd2(a0, sx(a0, 8));  a1 = __hadd2(a1, sx(a1, 8));
    a2 = __hadd2(a2, sx(a2, 8));  a3 = __hadd2(a3, sx(a3, 8));
    a0 = __hadd2(a0, sx(a0, 16)); a1 = __hadd2(a1, sx(a1, 16));
    a2 = __hadd2(a2, sx(a2, 16)); a3 = __hadd2(a3, sx(a3, 16));
    a0 = __hadd2(a0, sx(a0, 32)); a1 = __hadd2(a1, sx(a1, 32));
    a2 = __hadd2(a2, sx(a2, 32)); a3 = __hadd2(a3, sx(a3, 32));
    uint4 outp = make_uint4(0, 0, 0, 0);
    if (oct == 0) {
        const uint4* R16 = (const uint4*)Rin;
        uint4 rr = R16[(size_t)node * 8 + sub];
        const float rd = deg > 0 ? 1.f / (float)deg : 0.f;
        float2 sA = __half22float2(a0), rA = __half22float2(*(const __half2*)&rr.x);
        float2 sB = __half22float2(a1), rB = __half22float2(*(const __half2*)&rr.y);
        float2 sC = __half22float2(a2), rC = __half22float2(*(const __half2*)&rr.z);
        float2 sD = __half22float2(a3), rD = __half22float2(*(const __half2*)&rr.w);
        outp.x = packh2(fmaxf(fmaf(sA.x, rd, rA.x), 0.f), fmaxf(fmaf(sA.y, rd, rA.y), 0.f));
        outp.y = packh2(fmaxf(fmaf(sB.x, rd, rB.x), 0.f), fmaxf(fmaf(sB.y, rd, rB.y), 0.f));
        outp.z = packh2(fmaxf(fmaf(sC.x, rd, rC.x), 0.f), fmaxf(fmaf(sC.y, rd, rC.y), 0.f));
        outp.w = packh2(fmaxf(fmaf(sD.x, rd, rD.x), 0.f), fmaxf(fmaf(sD.y, rd, rD.y), 0.f));
    }
    return outp;
}

// ================= kernel 1: csr_mega =================
// blocks [0, NBLK1): CSR build — hist, barrier, scanA(+ticket scanB), barrier,
//                    scatter, barrier, p2. Software barriers (all 512 co-resident).
// blocks [NBLK1, NBLK1+MMBLK): layer-1 MFMA lift (independent, no barriers).
__global__ void __launch_bounds__(256, 3) csr_mega(
        const void* __restrict__ edge, int* __restrict__ flag, u32* __restrict__ gate,
        u32* __restrict__ bar, u32* __restrict__ barT,
        u32* __restrict__ blockSums, u32* __restrict__ SB,
        u32* __restrict__ HG, u32* __restrict__ P,
        u32* __restrict__ offs, int* __restrict__ ss,
        float* __restrict__ pool, u32* __restrict__ ticket3, u32* __restrict__ ticket4,
        int E, int n, int nb1, int nbScan,
        const float* __restrict__ X, const float* __restrict__ Wl,
        const float* __restrict__ Wr, const float* __restrict__ Bv,
        u16* __restrict__ Z, u16* __restrict__ R) {
    const int tid = threadIdx.x;
    if (blockIdx.x >= NBLK1) {
        // ---- mm1 (layer-1 lift, f32 input) — no gate/barrier participation ----
        const int waveId = (blockIdx.x - NBLK1) * 4 + (tid >> 6);
        mm_body<float>(X, Wl, Wr, Bv, Z, R, n, waveId, MMBLK * 4);
        return;
    }
    __shared__ u32 sh[768];
    __shared__ int shMisc;
    // ---- gate: block 0 zero-inits counters + pool, publishes MAGIC ----
    if (blockIdx.x == 0) {
        for (int i = tid; i < 4096; i += 256) pool[i] = 0.f;
        if (tid == 0) {
            bar[0] = 0; bar[1] = 0; bar[2] = 0;
            *barT = 0; *ticket3 = 0; *ticket4 = 0;
            __threadfence();
            atomicExch(gate, GATE_MAGIC);
        }
        __syncthreads();
    } else {
        if (tid == 0) {
            while (atomicAdd(gate, 0u) != GATE_MAGIC) __builtin_amdgcn_s_sleep(2);
        }
        __syncthreads();
        __threadfence();
    }
    const int w64 = detect_w64((const int*)edge, E, tid, &shMisc);
    if (blockIdx.x == 0 && tid == 0) flag[0] = w64;
    const int chunk = (E + NBLK1 - 1) / NBLK1;
    const int es = blockIdx.x * chunk;
    const int ee = min(es + chunk, E);
    // ---- phase 0: hist ----
    sh[tid] = 0;
    __syncthreads();
    for (int i = es + tid; i < ee; i += 256) {
        int d = gidx(edge, (long long)E + i, w64);
        if ((unsigned)d >= (unsigned)n) d = 0;
        atomicAdd(&sh[d >> 9], 1);
    }
    __syncthreads();
    for (int b = tid; b < nb1; b += 256) HG[b * NBLK1 + blockIdx.x] = sh[b];
    gbar(&bar[0], NBLK1);
    // ---- phase 1: scanA over NS (blocks < nbScan) + ticketed scanB ----
    if (blockIdx.x < nbScan) {
        const int NS = nb1 * NBLK1;
        const int ITEMS = 8;
        int base = blockIdx.x * 2048 + tid * ITEMS;
        u32 v[ITEMS];
        u32 sum = 0;
#pragma unroll
        for (int i = 0; i < ITEMS; ++i) {
            int idx = base + i;
            v[i] = (idx < NS) ? HG[idx] : 0;
            sum += v[i];
        }
        sh[tid] = sum;
        __syncthreads();
        u32 incl = sum;
        for (int d = 1; d < 256; d <<= 1) {
            u32 y = 0;
            if (tid >= d) y = sh[tid - d];
            __syncthreads();
            incl += y;
            sh[tid] = incl;
            __syncthreads();
        }
        u32 run = incl - sum;
#pragma unroll
        for (int i = 0; i < ITEMS; ++i) {
            int idx = base + i;
            if (idx < NS) HG[idx] = run;
            run += v[i];
        }
        if (tid == 255) {
            atomicExch(&blockSums[blockIdx.x], incl);
            __threadfence();
            u32 t = atomicAdd(barT, 1u);
            shMisc = (t == (u32)(nbScan - 1));
        }
        __syncthreads();
        if (shMisc) {
            u32 bv = (tid < nbScan) ? atomicAdd(&blockSums[tid], 0u) : 0;
            sh[tid] = bv;
            __syncthreads();
            u32 bincl = bv;
            for (int d = 1; d < 256; d <<= 1) {
                u32 y = 0;
                if (tid >= d) y = sh[tid - d];
                __syncthreads();
                bincl += y;
                sh[tid] = bincl;
                __syncthreads();
            }
            if (tid < nbScan) SB[tid] = bincl - bv;
        }
    }
    gbar(&bar[1], NBLK1);
    // ---- phase 2: scatter (rank via LDS atomics; packed (dst&511)<<17|src) ----
    {
        u32* base = sh;        // [0,256)
        u32* cur = sh + 256;   // [256,512)
        cur[tid] = 0;
        for (int b = tid; b < nb1; b += 256) {
            int i = b * NBLK1 + blockIdx.x;
            base[b] = HG[i] + SB[i >> 11];
        }
        __syncthreads();
        for (int i = es + tid; i < ee; i += 256) {
            int d = gidx(edge, (long long)E + i, w64);
            if ((unsigned)d >= (unsigned)n) d = 0;
            int sv = gidx(edge, i, w64);
            if ((unsigned)sv >= (unsigned)n) sv = 0;
            const int b1 = d >> 9;
            u32 r = atomicAdd(&cur[b1], 1);
            P[base[b1] + r] = (u32)sv | ((u32)(d & 511) << 17);
        }
    }
    gbar(&bar[2], NBLK1);
    // ---- phase 3: p2 (blocks < nb1) — fine hist(512), LDS scan, offs + final ss ----
    if (blockIdx.x >= nb1) return;
    {
        u32* h2 = sh;          // [0,512)
        u32* ts = sh + 512;    // [512,768)
        const int b = blockIdx.x;
        const int i0 = b * NBLK1;
        const int bs = (int)(HG[i0] + SB[i0 >> 11]);
        int be;
        if (b + 1 < nb1) {
            const int i1 = (b + 1) * NBLK1;
            be = (int)(HG[i1] + SB[i1 >> 11]);
        } else be = E;
        h2[tid] = 0;
        h2[tid + 256] = 0;
        __syncthreads();
        for (int i = bs + tid; i < be; i += 256) atomicAdd(&h2[(P[i] >> 17) & 511], 1);
        __syncthreads();
        u32 v0 = h2[2 * tid], v1 = h2[2 * tid + 1];
        u32 sum = v0 + v1;
        ts[tid] = sum;
        __syncthreads();
        u32 incl = sum;
        for (int d = 1; d < 256; d <<= 1) {
            u32 y = 0;
            if (tid >= d) y = ts[tid - d];
            __syncthreads();
            incl += y;
            ts[tid] = incl;
            __syncthreads();
        }
        u32 run = incl - sum;
        h2[2 * tid] = run;
        h2[2 * tid + 1] = run + v0;
        const int node0 = b * 512 + 2 * tid;
        if (node0 < n) offs[node0] = bs + run;
        if (node0 + 1 < n) offs[node0 + 1] = bs + run + v0;
        if (b == 0 && tid == 0) offs[n] = (u32)E;
        __syncthreads();
        for (int i = bs + tid; i < be; i += 256) {
            u32 p = P[i];
            u32 r = atomicAdd(&h2[(p >> 17) & 511], 1);
            ss[bs + r] = (int)(p & 0x1FFFFu);
        }
    }
}

// ================= kernels 2/4: aggregation (layers 1,2) =================
__global__ void __launch_bounds__(256) agg_kernel(const u16* __restrict__ Zin,
                                                  const u16* __restrict__ Rin,
                                                  const u32* __restrict__ offs,
                                                  const int* __restrict__ ss,
                                                  u16* __restrict__ Hout, int n) {
    const int lane = threadIdx.x & 63;
    const int oct = lane >> 3, sub = lane & 7;
    const int node = (blockIdx.x << 2) | (threadIdx.x >> 6);
    if (node >= n) return;
    uint4 outp = agg_node(Zin, Rin, offs, ss, node, lane, oct, sub);
    if (oct == 0)
        *(uint4*)(((u32*)Hout) + (size_t)node * 32 + 4 * sub) = outp;
}

// ================= kernels 3/5: MFMA lift (layers 2,3) =================
__global__ void __launch_bounds__(256) mm_mfma_kernel(const u16* __restrict__ X,
                                                      const float* __restrict__ Wl,
                                                      const float* __restrict__ Wr,
                                                      const float* __restrict__ Bv,
                                                      u16* __restrict__ Z,
                                                      u16* __restrict__ R, int n) {
    const int waveId = blockIdx.x * 4 + (threadIdx.x >> 6);
    mm_body<u16>(X, Wl, Wr, Bv, Z, R, n, waveId, MMBLK * 4);
}

// ================= kernel 6: agg3 + pool + head (last-arriver election) =================
__global__ void __launch_bounds__(256) agg3_pool_head(
        const u16* __restrict__ Zin, const u16* __restrict__ Rin,
        const u32* __restrict__ offs, const int* __restrict__ ss,
        u16* __restrict__ Hout,
        const void* __restrict__ batch, const int* __restrict__ flag,
        float* __restrict__ pool, u32* __restrict__ ticket3, u32* __restrict__ ticket4,
        const float* __restrict__ Wc1, const float* __restrict__ bc1,
        const float* __restrict__ Wc2, const float* __restrict__ bc2,
        float* __restrict__ out, int n, int npool) {
    const int tid = threadIdx.x;
    const int lane = tid & 63, wave = tid >> 6;
    const int oct = lane >> 3, sub = lane & 7;
    // ---- phase A: layer-3 aggregation ----
    const int node = (blockIdx.x << 2) | wave;
    if (node < n) {
        uint4 outp = agg_node(Zin, Rin, offs, ss, node, lane, oct, sub);
        if (oct == 0)
            *(uint4*)(((u32*)Hout) + (size_t)node * 32 + 4 * sub) = outp;
    }
    __threadfence();
    __syncthreads();
    __shared__ int rank;
    if (tid == 0) {
        u32 t = atomicAdd(ticket3, 1u);
        rank = (int)t - (int)(gridDim.x - npool);
    }
    __syncthreads();
    if (rank < 0) return;               // not among last npool arrivers
    if (tid == 0) {
        while (atomicAdd(ticket3, 0u) < gridDim.x) __builtin_amdgcn_s_sleep(2);
    }
    __syncthreads();
    __threadfence();
    // ---- phase B: pool (this block covers rows [rank*256, rank*256+256)) ----
    const int w64 = flag[0];
    {
        int start = (rank * 4 + wave) * 64;
        int end = min(start + 64, n);
        if (start < end) {
            float acc = 0.f;
            int cur = gidx(batch, start, w64) & 63;
            for (int i = start; i < end; ++i) {
                int g = gidx(batch, i, w64) & 63;
                if (g != cur) {
                    atomicAdd(&pool[cur * 64 + lane], acc);
                    acc = 0.f;
                    cur = g;
                }
                acc += __half2float(__ushort_as_half(Hout[(size_t)i * 64 + lane]));
            }
            atomicAdd(&pool[cur * 64 + lane], acc);
        }
    }
    __threadfence();
    __syncthreads();
    __shared__ int doHead;
    if (tid == 0) {
        u32 t2 = atomicAdd(ticket4, 1u);
        doHead = (t2 == (u32)(npool - 1));
    }
    __syncthreads();
    if (!doHead) return;
    __threadfence();
    // ---- phase C: head MLP (single block) ----
    __shared__ float gm[64 * 64];
    __shared__ float am[64 * 32];
    __shared__ int cnts[64];
    if (tid < 64) {
        int lo = 0, hi = n;
        while (lo < hi) { int mid = (lo + hi) >> 1; if (gidx(batch, mid, w64) < tid) lo = mid + 1; else hi = mid; }
        int lo2 = 0, hi2 = n;
        int v2 = tid + 1;
        while (lo2 < hi2) { int mid = (lo2 + hi2) >> 1; if (gidx(batch, mid, w64) < v2) lo2 = mid + 1; else hi2 = mid; }
        cnts[tid] = lo2 - lo;
    }
    __syncthreads();
    for (int i = tid; i < 4096; i += 256) {
        int g = i >> 6;
        float c = (float)(cnts[g] > 0 ? cnts[g] : 1);
        gm[i] = pool[i] / c;
    }
    __syncthreads();
    for (int i = tid; i < 64 * 32; i += 256) {
        int g = i >> 5, j = i & 31;
        float acc = bc1[j];
        for (int k = 0; k < 64; ++k) acc += gm[g * 64 + k] * Wc1[k * 32 + j];
        am[i] = acc > 0.f ? acc : 0.f;
    }
    __syncthreads();
    if (tid < 128) {
        int g = tid >> 1, o = tid & 1;
        float acc = bc2[o];
        for (int j = 0; j < 32; ++j) acc += am[g * 32 + j] * Wc2[j * 2 + o];
        out[tid] = acc;
    }
}

extern "C" void kernel_launch(void* const* d_in, const int* in_sizes, int n_in,
                              void* d_out, int out_size, void* d_ws, size_t ws_size,
                              hipStream_t stream) {
    const float* x   = (const float*)d_in[0];
    const void* edge = d_in[1];     // int32 or int64, auto-detected
    const void* batch = d_in[2];
    const float* W1l = (const float*)d_in[3];
    const float* b1  = (const float*)d_in[4];
    const float* W1r = (const float*)d_in[5];
    const float* W2l = (const float*)d_in[6];
    const float* b2  = (const float*)d_in[7];
    const float* W2r = (const float*)d_in[8];
    const float* W3l = (const float*)d_in[9];
    const float* b3  = (const float*)d_in[10];
    const float* W3r = (const float*)d_in[11];
    const float* Wc1 = (const float*)d_in[12];
    const float* bc1 = (const float*)d_in[13];
    const float* Wc2 = (const float*)d_in[14];
    const float* bc2 = (const float*)d_in[15];

    const int n = in_sizes[0] / 64;   // 100000
    const int E = in_sizes[1] / 2;    // 1600000
    const int nb1 = (n + 511) >> 9;   // 196 coarse buckets (requires <= 256)
    const int NS = nb1 * NBLK1;
    const int nbScan = (NS + 2047) / 2048;   // 49
    const int npool = (n + 255) >> 8;        // 391

    char* w = (char*)d_ws;
    size_t o = 0;
    auto take = [&](size_t bytes) -> void* {
        void* p = w + o;
        o = (o + bytes + 511) & ~(size_t)511;
        return p;
    };
    int* flag      = (int*)take(sizeof(int));
    u32* gate      = (u32*)take(sizeof(u32));
    u32* bar       = (u32*)take(4 * sizeof(u32));
    u32* barT      = (u32*)take(sizeof(u32));
    u32* ticket3   = (u32*)take(sizeof(u32));
    u32* ticket4   = (u32*)take(sizeof(u32));
    u32* offs      = (u32*)take((size_t)(n + 1) * sizeof(u32));
    u32* HG        = (u32*)take((size_t)(NS + 1) * sizeof(u32));
    u32* blockSums = (u32*)take(256 * sizeof(u32));
    u32* SB        = (u32*)take(256 * sizeof(u32));
    u32* P         = (u32*)take((size_t)E * sizeof(u32));
    int* ss        = (int*)take((size_t)E * sizeof(int));
    u16* Z         = (u16*)take((size_t)n * 64 * sizeof(u16));
    u16* R         = (u16*)take((size_t)n * 64 * sizeof(u16));
    u16* HA        = (u16*)take((size_t)n * 64 * sizeof(u16));
    u16* HB        = (u16*)take((size_t)n * 64 * sizeof(u16));
    float* pool    = (float*)take(64 * 64 * sizeof(float));

    // 1. CSR build (hist ∥ layer-1 lift, scan, scatter, p2) — one launch
    csr_mega<<<NBLK1 + MMBLK, 256, 0, stream>>>(edge, flag, gate, bar, barT,
                                                blockSums, SB, HG, P, offs, ss,
                                                pool, ticket3, ticket4,
                                                E, n, nb1, nbScan,
                                                x, W1l, W1r, b1, Z, R);
    const int nodeBlocks = (n + 3) / 4;
    // 2-5. layer pipeline
    agg_kernel<<<nodeBlocks, 256, 0, stream>>>(Z, R, offs, ss, HA, n);
    mm_mfma_kernel<<<MMBLK, 256, 0, stream>>>(HA, W2l, W2r, b2, Z, R, n);
    agg_kernel<<<nodeBlocks, 256, 0, stream>>>(Z, R, offs, ss, HB, n);
    mm_mfma_kernel<<<MMBLK, 256, 0, stream>>>(HB, W3l, W3r, b3, Z, R, n);
    // 6. layer-3 agg + pool + head — one launch
    agg3_pool_head<<<nodeBlocks, 256, 0, stream>>>(Z, R, offs, ss, HA,
                                                   batch, flag, pool, ticket3, ticket4,
                                                   Wc1, bc1, Wc2, bc2,
                                                   (float*)d_out, n, npool);
}

// Round 14
// 725.553 us; speedup vs baseline: 3.9117x; 3.9117x over previous
//
#include <hip/hip_runtime.h>
#include <hip/hip_bf16.h>
#include <hip/hip_fp16.h>

typedef unsigned int u32;
typedef unsigned short u16;
typedef _Float16 f16x8 __attribute__((ext_vector_type(8)));
typedef float f32x4 __attribute__((ext_vector_type(4)));

#define NBLK1 512        // CSR blocks (edge chunks)
#define MMBLK 256        // mm blocks / mm1 side of csr_mega
#define GATE_MAGIC 0x13572468u

// ---------- fp16 pack/unpack ----------
__device__ __forceinline__ u16 f2h(float f) { return __half_as_ushort(__float2half(f)); }
__device__ __forceinline__ u32 packh2(float a, float b) {
    return (u32)f2h(a) | ((u32)f2h(b) << 16);
}
__device__ __forceinline__ __half2 sx(__half2 v, int m) {
    int iv = __shfl_xor(*(int*)&v, m, 64);
    return *(__half2*)&iv;
}

// ---------- int-width-agnostic index load (w64=1 -> int64 data on device) ----------
__device__ __forceinline__ int gidx(const void* p, long long i, int w64) {
    if (w64) return (int)((const long long*)p)[i];
    return ((const int*)p)[i];
}

// per-block int64 detection (probe odd words; int32 data -> some nonzero, int64 -> all zero)
__device__ __forceinline__ int detect_w64(const int* edge_words, int E, int tid, int* sh) {
    if (tid == 0) *sh = 0;
    __syncthreads();
    const long long totalWords = 2LL * E;
    const long long step = totalWords / 256;
    long long w = ((long long)tid * step) | 1;
    int nz = (w < totalWords) ? edge_words[w] : 0;
    if (nz) atomicOr(sh, 1);
    __syncthreads();
    return (*sh) ? 0 : 1;
}

// device-scope software barrier among `target` co-resident blocks
__device__ __forceinline__ void gbar(u32* bar, u32 target) {
    __threadfence();
    __syncthreads();
    if (threadIdx.x == 0) {
        atomicAdd(bar, 1u);
        while (atomicAdd(bar, 0u) < target) __builtin_amdgcn_s_sleep(2);
    }
    __syncthreads();
    __threadfence();
}

// ---------- MFMA lift body ----------
template <typename T>
__device__ __forceinline__ void mm_body(const T* __restrict__ X,
                                        const float* __restrict__ Wl,
                                        const float* __restrict__ Wr,
                                        const float* __restrict__ Bv,
                                        u16* __restrict__ Z, u16* __restrict__ R,
                                        int n, int waveId, int nwaves) {
    const int lane = threadIdx.x & 63;
    const int quad = lane >> 4;
    const int m16 = lane & 15;
    f16x8 bl[2][4], br[2][4];
#pragma unroll
    for (int kh = 0; kh < 2; ++kh)
#pragma unroll
        for (int t = 0; t < 4; ++t)
#pragma unroll
            for (int j = 0; j < 8; ++j) {
                int k = kh * 32 + quad * 8 + j;
                int c = t * 16 + m16;
                bl[kh][t][j] = (_Float16)Wl[k * 64 + c];
                br[kh][t][j] = (_Float16)Wr[k * 64 + c];
            }
    float bias_t[4];
#pragma unroll
    for (int t = 0; t < 4; ++t) bias_t[t] = Bv[t * 16 + m16];

    const int ntiles = (n + 15) >> 4;
    for (int tile = waveId; tile < ntiles; tile += nwaves) {
        const int nodeBase = tile << 4;
        int nodeA = nodeBase + m16;
        if (nodeA >= n) nodeA = n - 1;
        f16x8 a[2];
        if constexpr (sizeof(T) == 2) {
            const _Float16* xp = (const _Float16*)X + (size_t)nodeA * 64;
#pragma unroll
            for (int kh = 0; kh < 2; ++kh)
                a[kh] = *(const f16x8*)(xp + kh * 32 + quad * 8);
        } else {
#pragma unroll
            for (int kh = 0; kh < 2; ++kh) {
                const float4* p = (const float4*)((const float*)X + (size_t)nodeA * 64 + kh * 32 + quad * 8);
                float4 x0 = p[0], x1 = p[1];
                a[kh][0] = (_Float16)x0.x; a[kh][1] = (_Float16)x0.y;
                a[kh][2] = (_Float16)x0.z; a[kh][3] = (_Float16)x0.w;
                a[kh][4] = (_Float16)x1.x; a[kh][5] = (_Float16)x1.y;
                a[kh][6] = (_Float16)x1.z; a[kh][7] = (_Float16)x1.w;
            }
        }
        f32x4 cl[4], cr[4];
#pragma unroll
        for (int t = 0; t < 4; ++t) {
            f32x4 c0 = {0.f, 0.f, 0.f, 0.f};
            c0 = __builtin_amdgcn_mfma_f32_16x16x32_f16(a[0], bl[0][t], c0, 0, 0, 0);
            c0 = __builtin_amdgcn_mfma_f32_16x16x32_f16(a[1], bl[1][t], c0, 0, 0, 0);
            cl[t] = c0;
            f32x4 c1 = {0.f, 0.f, 0.f, 0.f};
            c1 = __builtin_amdgcn_mfma_f32_16x16x32_f16(a[0], br[0][t], c1, 0, 0, 0);
            c1 = __builtin_amdgcn_mfma_f32_16x16x32_f16(a[1], br[1][t], c1, 0, 0, 0);
            cr[t] = c1;
        }
#pragma unroll
        for (int rg = 0; rg < 4; ++rg) {
            const int node = nodeBase + quad * 4 + rg;
            if (node < n) {
#pragma unroll
                for (int t = 0; t < 4; ++t) {
                    const int c = t * 16 + m16;
                    Z[(size_t)node * 64 + c] = f2h(cl[t][rg]);
                    R[(size_t)node * 64 + c] = f2h(cr[t][rg] + bias_t[t]);
                }
            }
        }
    }
}

// ---------- agg body: relu(mean_neighbors(Z) + R); oct layout, uint4 gathers ----------
__device__ __forceinline__ uint4 agg_node(const u16* __restrict__ Zin,
                                          const u16* __restrict__ Rin,
                                          const u32* __restrict__ offs,
                                          const int* __restrict__ ss,
                                          int node, int lane, int oct, int sub) {
    const uint4* Z16 = (const uint4*)Zin;
    const int off = (int)offs[node], end = (int)offs[node + 1];
    const int deg = end - off;
    const __half2 zero2 = __float2half2_rn(0.f);
    const __half2 one2 = __float2half2_rn(1.f);
    __half2 a0 = zero2, a1 = zero2, a2 = zero2, a3 = zero2;
    __half2 b0 = zero2, b1 = zero2, b2 = zero2, b3 = zero2;
    for (int base = off; base < end; base += 64) {
        const int cnt = min(64, end - base);
        const int idx = ss[base + (lane < cnt ? lane : cnt - 1)];
        int p = 0;
        for (; p + 16 <= cnt; p += 16) {
            int s0 = __shfl(idx, p + oct, 64);
            int s1 = __shfl(idx, p + 8 + oct, 64);
            uint4 u0 = Z16[(size_t)s0 * 8 + sub];
            uint4 u1 = Z16[(size_t)s1 * 8 + sub];
            a0 = __hadd2(a0, *(const __half2*)&u0.x);
            a1 = __hadd2(a1, *(const __half2*)&u0.y);
            a2 = __hadd2(a2, *(const __half2*)&u0.z);
            a3 = __hadd2(a3, *(const __half2*)&u0.w);
            b0 = __hadd2(b0, *(const __half2*)&u1.x);
            b1 = __hadd2(b1, *(const __half2*)&u1.y);
            b2 = __hadd2(b2, *(const __half2*)&u1.z);
            b3 = __hadd2(b3, *(const __half2*)&u1.w);
        }
        const int rem = cnt - p;
        if (rem) {
            int j = p + oct;
            int s0 = __shfl(idx, j < cnt ? j : cnt - 1, 64);
            uint4 u0 = Z16[(size_t)s0 * 8 + sub];
            __half2 m0 = (j < cnt) ? one2 : zero2;
            a0 = __hfma2(*(const __half2*)&u0.x, m0, a0);
            a1 = __hfma2(*(const __half2*)&u0.y, m0, a1);
            a2 = __hfma2(*(const __half2*)&u0.z, m0, a2);
            a3 = __hfma2(*(const __half2*)&u0.w, m0, a3);
            if (rem > 8) {
                int j1 = p + 8 + oct;
                int s1 = __shfl(idx, j1 < cnt ? j1 : cnt - 1, 64);
                uint4 u1 = Z16[(size_t)s1 * 8 + sub];
                __half2 m1 = (j1 < cnt) ? one2 : zero2;
                b0 = __hfma2(*(const __half2*)&u1.x, m1, b0);
                b1 = __hfma2(*(const __half2*)&u1.y, m1, b1);
                b2 = __hfma2(*(const __half2*)&u1.z, m1, b2);
                b3 = __hfma2(*(const __half2*)&u1.w, m1, b3);
            }
        }
    }
    a0 = __hadd2(a0, b0); a1 = __hadd2(a1, b1);
    a2 = __hadd2(a2, b2); a3 = __hadd2(a3, b3);
    a0 = __hadd2(a0, sx(a0, 8));  a1 = __hadd2(a1, sx(a1, 8));
    a2 = __hadd2(a2, sx(a2, 8));  a3 = __hadd2(a3, sx(a3, 8));
    a0 = __hadd2(a0, sx(a0, 16)); a1 = __hadd2(a1, sx(a1, 16));
    a2 = __hadd2(a2, sx(a2, 16)); a3 = __hadd2(a3, sx(a3, 16));
    a0 = __hadd2(a0, sx(a0, 32)); a1 = __hadd2(a1, sx(a1, 32));
    a2 = __hadd2(a2, sx(a2, 32)); a3 = __hadd2(a3, sx(a3, 32));
    uint4 outp = make_uint4(0, 0, 0, 0);
    if (oct == 0) {
        const uint4* R16 = (const uint4*)Rin;
        uint4 rr = R16[(size_t)node * 8 + sub];
        const float rd = deg > 0 ? 1.f / (float)deg : 0.f;
        float2 sA = __half22float2(a0), rA = __half22float2(*(const __half2*)&rr.x);
        float2 sB = __half22float2(a1), rB = __half22float2(*(const __half2*)&rr.y);
        float2 sC = __half22float2(a2), rC = __half22float2(*(const __half2*)&rr.z);
        float2 sD = __half22float2(a3), rD = __half22float2(*(const __half2*)&rr.w);
        outp.x = packh2(fmaxf(fmaf(sA.x, rd, rA.x), 0.f), fmaxf(fmaf(sA.y, rd, rA.y), 0.f));
        outp.y = packh2(fmaxf(fmaf(sB.x, rd, rB.x), 0.f), fmaxf(fmaf(sB.y, rd, rB.y), 0.f));
        outp.z = packh2(fmaxf(fmaf(sC.x, rd, rC.x), 0.f), fmaxf(fmaf(sC.y, rd, rC.y), 0.f));
        outp.w = packh2(fmaxf(fmaf(sD.x, rd, rD.x), 0.f), fmaxf(fmaf(sD.y, rd, rD.y), 0.f));
    }
    return outp;
}

// ================= kernel 1: csr_mega =================
// blocks [0, NBLK1): CSR build — hist, gbar, scan(+ticketed top-scan), gbar,
//                    scatter, gbar, p2. All 512 co-resident (launch_bounds 256,3).
// blocks [NBLK1, NBLK1+MMBLK): layer-1 MFMA lift (independent, no barriers).
__global__ void __launch_bounds__(256, 3) csr_mega(
        const void* __restrict__ edge, int* __restrict__ flag, u32* __restrict__ gate,
        u32* __restrict__ bar, u32* __restrict__ barT,
        u32* __restrict__ blockSums, u32* __restrict__ SB,
        u32* __restrict__ HG, u32* __restrict__ P,
        u32* __restrict__ offs, int* __restrict__ ss,
        float* __restrict__ pool, u32* __restrict__ ticketP,
        int E, int n, int nb1, int nbScan,
        const float* __restrict__ X, const float* __restrict__ Wl,
        const float* __restrict__ Wr, const float* __restrict__ Bv,
        u16* __restrict__ Z, u16* __restrict__ R) {
    const int tid = threadIdx.x;
    if (blockIdx.x >= NBLK1) {
        const int waveId = (blockIdx.x - NBLK1) * 4 + (tid >> 6);
        mm_body<float>(X, Wl, Wr, Bv, Z, R, n, waveId, MMBLK * 4);
        return;
    }
    __shared__ u32 sh[768];
    __shared__ int shMisc;
    if (blockIdx.x == 0) {
        for (int i = tid; i < 4096; i += 256) pool[i] = 0.f;
        if (tid == 0) {
            bar[0] = 0; bar[1] = 0; bar[2] = 0;
            *barT = 0; *ticketP = 0;
            __threadfence();
            atomicExch(gate, GATE_MAGIC);
        }
        __syncthreads();
    } else {
        if (tid == 0) {
            while (atomicAdd(gate, 0u) != GATE_MAGIC) __builtin_amdgcn_s_sleep(2);
        }
        __syncthreads();
        __threadfence();
    }
    const int w64 = detect_w64((const int*)edge, E, tid, &shMisc);
    if (blockIdx.x == 0 && tid == 0) flag[0] = w64;
    const int chunk = (E + NBLK1 - 1) / NBLK1;
    const int es = blockIdx.x * chunk;
    const int ee = min(es + chunk, E);
    // ---- phase 0: hist ----
    sh[tid] = 0;
    __syncthreads();
    for (int i = es + tid; i < ee; i += 256) {
        int d = gidx(edge, (long long)E + i, w64);
        if ((unsigned)d >= (unsigned)n) d = 0;
        atomicAdd(&sh[d >> 9], 1);
    }
    __syncthreads();
    for (int b = tid; b < nb1; b += 256) HG[b * NBLK1 + blockIdx.x] = sh[b];
    gbar(&bar[0], NBLK1);
    // ---- phase 1: scan over NS (blocks < nbScan) + ticketed top scan ----
    if (blockIdx.x < nbScan) {
        const int NS = nb1 * NBLK1;
        const int ITEMS = 8;
        int base = blockIdx.x * 2048 + tid * ITEMS;
        u32 v[ITEMS];
        u32 sum = 0;
#pragma unroll
        for (int i = 0; i < ITEMS; ++i) {
            int idx = base + i;
            v[i] = (idx < NS) ? HG[idx] : 0;
            sum += v[i];
        }
        sh[tid] = sum;
        __syncthreads();
        u32 incl = sum;
        for (int d = 1; d < 256; d <<= 1) {
            u32 y = 0;
            if (tid >= d) y = sh[tid - d];
            __syncthreads();
            incl += y;
            sh[tid] = incl;
            __syncthreads();
        }
        u32 run = incl - sum;
#pragma unroll
        for (int i = 0; i < ITEMS; ++i) {
            int idx = base + i;
            if (idx < NS) HG[idx] = run;
            run += v[i];
        }
        if (tid == 255) {
            atomicExch(&blockSums[blockIdx.x], incl);
            __threadfence();
            u32 t = atomicAdd(barT, 1u);
            shMisc = (t == (u32)(nbScan - 1));
        }
        __syncthreads();
        if (shMisc) {
            u32 bv = (tid < nbScan) ? atomicAdd(&blockSums[tid], 0u) : 0;
            sh[tid] = bv;
            __syncthreads();
            u32 bincl = bv;
            for (int d = 1; d < 256; d <<= 1) {
                u32 y = 0;
                if (tid >= d) y = sh[tid - d];
                __syncthreads();
                bincl += y;
                sh[tid] = bincl;
                __syncthreads();
            }
            if (tid < nbScan) SB[tid] = bincl - bv;
        }
    }
    gbar(&bar[1], NBLK1);
    // ---- phase 2: scatter ----
    {
        u32* base = sh;
        u32* cur = sh + 256;
        cur[tid] = 0;
        for (int b = tid; b < nb1; b += 256) {
            int i = b * NBLK1 + blockIdx.x;
            base[b] = HG[i] + SB[i >> 11];
        }
        __syncthreads();
        for (int i = es + tid; i < ee; i += 256) {
            int d = gidx(edge, (long long)E + i, w64);
            if ((unsigned)d >= (unsigned)n) d = 0;
            int sv = gidx(edge, i, w64);
            if ((unsigned)sv >= (unsigned)n) sv = 0;
            const int b1 = d >> 9;
            u32 r = atomicAdd(&cur[b1], 1);
            P[base[b1] + r] = (u32)sv | ((u32)(d & 511) << 17);
        }
    }
    gbar(&bar[2], NBLK1);
    // ---- phase 3: p2 (blocks < nb1) ----
    if (blockIdx.x >= nb1) return;
    {
        u32* h2 = sh;
        u32* ts = sh + 512;
        const int b = blockIdx.x;
        const int i0 = b * NBLK1;
        const int bs = (int)(HG[i0] + SB[i0 >> 11]);
        int be;
        if (b + 1 < nb1) {
            const int i1 = (b + 1) * NBLK1;
            be = (int)(HG[i1] + SB[i1 >> 11]);
        } else be = E;
        h2[tid] = 0;
        h2[tid + 256] = 0;
        __syncthreads();
        for (int i = bs + tid; i < be; i += 256) atomicAdd(&h2[(P[i] >> 17) & 511], 1);
        __syncthreads();
        u32 v0 = h2[2 * tid], v1 = h2[2 * tid + 1];
        u32 sum = v0 + v1;
        ts[tid] = sum;
        __syncthreads();
        u32 incl = sum;
        for (int d = 1; d < 256; d <<= 1) {
            u32 y = 0;
            if (tid >= d) y = ts[tid - d];
            __syncthreads();
            incl += y;
            ts[tid] = incl;
            __syncthreads();
        }
        u32 run = incl - sum;
        h2[2 * tid] = run;
        h2[2 * tid + 1] = run + v0;
        const int node0 = b * 512 + 2 * tid;
        if (node0 < n) offs[node0] = bs + run;
        if (node0 + 1 < n) offs[node0 + 1] = bs + run + v0;
        if (b == 0 && tid == 0) offs[n] = (u32)E;
        __syncthreads();
        for (int i = bs + tid; i < be; i += 256) {
            u32 p = P[i];
            u32 r = atomicAdd(&h2[(p >> 17) & 511], 1);
            ss[bs + r] = (int)(p & 0x1FFFFu);
        }
    }
}

// ================= aggregation (layers 1,2,3) =================
__global__ void __launch_bounds__(256) agg_kernel(const u16* __restrict__ Zin,
                                                  const u16* __restrict__ Rin,
                                                  const u32* __restrict__ offs,
                                                  const int* __restrict__ ss,
                                                  u16* __restrict__ Hout, int n) {
    const int lane = threadIdx.x & 63;
    const int oct = lane >> 3, sub = lane & 7;
    const int node = (blockIdx.x << 2) | (threadIdx.x >> 6);
    if (node >= n) return;
    uint4 outp = agg_node(Zin, Rin, offs, ss, node, lane, oct, sub);
    if (oct == 0)
        *(uint4*)(((u32*)Hout) + (size_t)node * 32 + 4 * sub) = outp;
}

// ================= MFMA lift (layers 2,3) =================
__global__ void __launch_bounds__(256) mm_mfma_kernel(const u16* __restrict__ X,
                                                      const float* __restrict__ Wl,
                                                      const float* __restrict__ Wr,
                                                      const float* __restrict__ Bv,
                                                      u16* __restrict__ Z,
                                                      u16* __restrict__ R, int n) {
    const int waveId = blockIdx.x * 4 + (threadIdx.x >> 6);
    mm_body<u16>(X, Wl, Wr, Bv, Z, R, n, waveId, MMBLK * 4);
}

// ================= pool + head (ticketed last block runs head, no spin) =========
__global__ void __launch_bounds__(256) pool_head_kernel(
        const u16* __restrict__ H, const void* __restrict__ batch,
        const int* __restrict__ flag, float* __restrict__ pool,
        u32* __restrict__ ticket,
        const float* __restrict__ Wc1, const float* __restrict__ bc1,
        const float* __restrict__ Wc2, const float* __restrict__ bc2,
        float* __restrict__ out, int n) {
    const int tid = threadIdx.x;
    const int lane = tid & 63, wave = tid >> 6;
    const int w64 = flag[0];
    // ---- pool phase: this block covers rows [blockIdx*256, +256) ----
    {
        int start = (blockIdx.x * 4 + wave) * 64;
        int end = min(start + 64, n);
        if (start < end) {
            float acc = 0.f;
            int cur = gidx(batch, start, w64) & 63;
            for (int i = start; i < end; ++i) {
                int g = gidx(batch, i, w64) & 63;
                if (g != cur) {
                    atomicAdd(&pool[cur * 64 + lane], acc);
                    acc = 0.f;
                    cur = g;
                }
                acc += __half2float(__ushort_as_half(H[(size_t)i * 64 + lane]));
            }
            atomicAdd(&pool[cur * 64 + lane], acc);
        }
    }
    __threadfence();
    __syncthreads();
    __shared__ int isLast;
    if (tid == 0) isLast = (atomicAdd(ticket, 1u) == (u32)(gridDim.x - 1));
    __syncthreads();
    if (!isLast) return;
    __threadfence();
    // ---- head phase (single block; all other blocks' pool adds are fenced) ----
    __shared__ float gm[64 * 64];
    __shared__ float am[64 * 32];
    __shared__ int cnts[64];
    if (tid < 64) {
        int lo = 0, hi = n;
        while (lo < hi) { int mid = (lo + hi) >> 1; if (gidx(batch, mid, w64) < tid) lo = mid + 1; else hi = mid; }
        int lo2 = 0, hi2 = n;
        int v2 = tid + 1;
        while (lo2 < hi2) { int mid = (lo2 + hi2) >> 1; if (gidx(batch, mid, w64) < v2) lo2 = mid + 1; else hi2 = mid; }
        cnts[tid] = lo2 - lo;
    }
    __syncthreads();
    for (int i = tid; i < 4096; i += 256) {
        int g = i >> 6;
        float c = (float)(cnts[g] > 0 ? cnts[g] : 1);
        gm[i] = pool[i] / c;
    }
    __syncthreads();
    for (int i = tid; i < 64 * 32; i += 256) {
        int g = i >> 5, j = i & 31;
        float acc = bc1[j];
        for (int k = 0; k < 64; ++k) acc += gm[g * 64 + k] * Wc1[k * 32 + j];
        am[i] = acc > 0.f ? acc : 0.f;
    }
    __syncthreads();
    if (tid < 128) {
        int g = tid >> 1, o = tid & 1;
        float acc = bc2[o];
        for (int j = 0; j < 32; ++j) acc += am[g * 32 + j] * Wc2[j * 2 + o];
        out[tid] = acc;
    }
}

extern "C" void kernel_launch(void* const* d_in, const int* in_sizes, int n_in,
                              void* d_out, int out_size, void* d_ws, size_t ws_size,
                              hipStream_t stream) {
    const float* x   = (const float*)d_in[0];
    const void* edge = d_in[1];     // int32 or int64, auto-detected
    const void* batch = d_in[2];
    const float* W1l = (const float*)d_in[3];
    const float* b1  = (const float*)d_in[4];
    const float* W1r = (const float*)d_in[5];
    const float* W2l = (const float*)d_in[6];
    const float* b2  = (const float*)d_in[7];
    const float* W2r = (const float*)d_in[8];
    const float* W3l = (const float*)d_in[9];
    const float* b3  = (const float*)d_in[10];
    const float* W3r = (const float*)d_in[11];
    const float* Wc1 = (const float*)d_in[12];
    const float* bc1 = (const float*)d_in[13];
    const float* Wc2 = (const float*)d_in[14];
    const float* bc2 = (const float*)d_in[15];

    const int n = in_sizes[0] / 64;   // 100000
    const int E = in_sizes[1] / 2;    // 1600000
    const int nb1 = (n + 511) >> 9;   // 196 coarse buckets
    const int NS = nb1 * NBLK1;
    const int nbScan = (NS + 2047) / 2048;   // 49
    const int npool = (n + 255) >> 8;        // 391

    char* w = (char*)d_ws;
    size_t o = 0;
    auto take = [&](size_t bytes) -> void* {
        void* p = w + o;
        o = (o + bytes + 511) & ~(size_t)511;
        return p;
    };
    int* flag      = (int*)take(sizeof(int));
    u32* gate      = (u32*)take(sizeof(u32));
    u32* bar       = (u32*)take(4 * sizeof(u32));
    u32* barT      = (u32*)take(sizeof(u32));
    u32* ticketP   = (u32*)take(sizeof(u32));
    u32* offs      = (u32*)take((size_t)(n + 1) * sizeof(u32));
    u32* HG        = (u32*)take((size_t)(NS + 1) * sizeof(u32));
    u32* blockSums = (u32*)take(256 * sizeof(u32));
    u32* SB        = (u32*)take(256 * sizeof(u32));
    u32* P         = (u32*)take((size_t)E * sizeof(u32));
    int* ss        = (int*)take((size_t)E * sizeof(int));
    u16* Z         = (u16*)take((size_t)n * 64 * sizeof(u16));
    u16* R         = (u16*)take((size_t)n * 64 * sizeof(u16));
    u16* HA        = (u16*)take((size_t)n * 64 * sizeof(u16));
    u16* HB        = (u16*)take((size_t)n * 64 * sizeof(u16));
    float* pool    = (float*)take(64 * 64 * sizeof(float));

    // 1. CSR build (hist ∥ layer-1 lift, scan, scatter, p2) — one launch
    csr_mega<<<NBLK1 + MMBLK, 256, 0, stream>>>(edge, flag, gate, bar, barT,
                                                blockSums, SB, HG, P, offs, ss,
                                                pool, ticketP,
                                                E, n, nb1, nbScan,
                                                x, W1l, W1r, b1, Z, R);
    const int nodeBlocks = (n + 3) / 4;
    // 2-6. layer pipeline
    agg_kernel<<<nodeBlocks, 256, 0, stream>>>(Z, R, offs, ss, HA, n);
    mm_mfma_kernel<<<MMBLK, 256, 0, stream>>>(HA, W2l, W2r, b2, Z, R, n);
    agg_kernel<<<nodeBlocks, 256, 0, stream>>>(Z, R, offs, ss, HB, n);
    mm_mfma_kernel<<<MMBLK, 256, 0, stream>>>(HB, W3l, W3r, b3, Z, R, n);
    agg_kernel<<<nodeBlocks, 256, 0, stream>>>(Z, R, offs, ss, HA, n);
    // 7. pool + head — one launch (ticketed last block runs head)
    pool_head_kernel<<<npool, 256, 0, stream>>>(HA, batch, flag, pool, ticketP,
                                                Wc1, bc1, Wc2, bc2,
                                                (float*)d_out, n);
}

// Round 15
// 363.862 us; speedup vs baseline: 7.8001x; 1.9940x over previous
//
#include <hip/hip_runtime.h>
#include <hip/hip_bf16.h>
#include <hip/hip_fp16.h>

typedef unsigned int u32;
typedef unsigned short u16;
typedef _Float16 f16x8 __attribute__((ext_vector_type(8)));
typedef float f32x4 __attribute__((ext_vector_type(4)));

#define NBLK1 512   // pass-1 blocks (edge chunks)
#define MMBLK 256   // mm blocks (1024 waves, ~6 tiles/wave: weight-frag setup amortized)

// ---------- fp16 pack/unpack ----------
__device__ __forceinline__ u16 f2h(float f) { return __half_as_ushort(__float2half(f)); }
__device__ __forceinline__ u32 packh2(float a, float b) {
    return (u32)f2h(a) | ((u32)f2h(b) << 16);
}
__device__ __forceinline__ __half2 sx(__half2 v, int m) {
    int iv = __shfl_xor(*(int*)&v, m, 64);
    return *(__half2*)&iv;
}

// ---------- int-width-agnostic index load (w64=1 -> int64 data on device) ----------
__device__ __forceinline__ int gidx(const void* p, long long i, int w64) {
    if (w64) return (int)((const long long*)p)[i];
    return ((const int*)p)[i];
}

// per-block int64 detection (probe odd words; int32 data -> some nonzero, int64 -> all zero)
__device__ __forceinline__ int detect_w64(const int* edge_words, int E, int tid, int* sh) {
    if (tid == 0) *sh = 0;
    __syncthreads();
    const long long totalWords = 2LL * E;
    const long long step = totalWords / 256;
    long long w = ((long long)tid * step) | 1;
    int nz = (w < totalWords) ? edge_words[w] : 0;
    if (nz) atomicOr(sh, 1);
    __syncthreads();
    return (*sh) ? 0 : 1;
}

// ---------- fused: p1_hist (blocks < NBLK1) + layer-1 MFMA lift (rest) ----------
__global__ void __launch_bounds__(256) fused_hist_mm1(
        const void* __restrict__ edge, int* __restrict__ flag, u32* __restrict__ ticket,
        u32* __restrict__ HG, int E, int n, int nb1,
        const float* __restrict__ X, const float* __restrict__ Wl,
        const float* __restrict__ Wr, const float* __restrict__ Bv,
        u16* __restrict__ Z, u16* __restrict__ R) {
    if (blockIdx.x < NBLK1) {
        __shared__ u32 h[256];
        __shared__ int shnz;
        const int tid = threadIdx.x;
        h[tid] = 0;
        const int w64 = detect_w64((const int*)edge, E, tid, &shnz);
        if (blockIdx.x == 0 && tid == 0) { flag[0] = w64; ticket[0] = 0; ticket[1] = 0; }
        __syncthreads();
        const int chunk = (E + NBLK1 - 1) / NBLK1;
        const int s = blockIdx.x * chunk;
        const int e = min(s + chunk, E);
        for (int i = s + tid; i < e; i += 256) {
            int d = gidx(edge, (long long)E + i, w64);
            if ((unsigned)d >= (unsigned)n) d = 0;
            atomicAdd(&h[d >> 9], 1);
        }
        __syncthreads();
        for (int b = tid; b < nb1; b += 256) HG[b * NBLK1 + blockIdx.x] = h[b];
        return;
    }
    const int lane = threadIdx.x & 63;
    const int quad = lane >> 4;
    const int m16 = lane & 15;
    f16x8 bl[2][4], br[2][4];
#pragma unroll
    for (int kh = 0; kh < 2; ++kh)
#pragma unroll
        for (int t = 0; t < 4; ++t)
#pragma unroll
            for (int j = 0; j < 8; ++j) {
                int k = kh * 32 + quad * 8 + j;
                int c = t * 16 + m16;
                bl[kh][t][j] = (_Float16)Wl[k * 64 + c];
                br[kh][t][j] = (_Float16)Wr[k * 64 + c];
            }
    float bias_t[4];
#pragma unroll
    for (int t = 0; t < 4; ++t) bias_t[t] = Bv[t * 16 + m16];

    const int ntiles = (n + 15) >> 4;
    const int nwaves = (gridDim.x - NBLK1) * 4;
    for (int tile = (blockIdx.x - NBLK1) * 4 + (threadIdx.x >> 6); tile < ntiles; tile += nwaves) {
        const int nodeBase = tile << 4;
        int nodeA = nodeBase + m16;
        if (nodeA >= n) nodeA = n - 1;
        f16x8 a[2];
#pragma unroll
        for (int kh = 0; kh < 2; ++kh) {
            const float4* p = (const float4*)(X + (size_t)nodeA * 64 + kh * 32 + quad * 8);
            float4 x0 = p[0], x1 = p[1];
            a[kh][0] = (_Float16)x0.x; a[kh][1] = (_Float16)x0.y;
            a[kh][2] = (_Float16)x0.z; a[kh][3] = (_Float16)x0.w;
            a[kh][4] = (_Float16)x1.x; a[kh][5] = (_Float16)x1.y;
            a[kh][6] = (_Float16)x1.z; a[kh][7] = (_Float16)x1.w;
        }
        f32x4 cl[4], cr[4];
#pragma unroll
        for (int t = 0; t < 4; ++t) {
            f32x4 c0 = {0.f, 0.f, 0.f, 0.f};
            c0 = __builtin_amdgcn_mfma_f32_16x16x32_f16(a[0], bl[0][t], c0, 0, 0, 0);
            c0 = __builtin_amdgcn_mfma_f32_16x16x32_f16(a[1], bl[1][t], c0, 0, 0, 0);
            cl[t] = c0;
            f32x4 c1 = {0.f, 0.f, 0.f, 0.f};
            c1 = __builtin_amdgcn_mfma_f32_16x16x32_f16(a[0], br[0][t], c1, 0, 0, 0);
            c1 = __builtin_amdgcn_mfma_f32_16x16x32_f16(a[1], br[1][t], c1, 0, 0, 0);
            cr[t] = c1;
        }
#pragma unroll
        for (int rg = 0; rg < 4; ++rg) {
            const int node = nodeBase + quad * 4 + rg;
            if (node < n) {
#pragma unroll
                for (int t = 0; t < 4; ++t) {
                    const int c = t * 16 + m16;
                    Z[(size_t)node * 64 + c] = f2h(cl[t][rg]);
                    R[(size_t)node * 64 + c] = f2h(cr[t][rg] + bias_t[t]);
                }
            }
        }
    }
}

// ---------- scanA with fused scanB (ticketed last block — single waiter, no spin) ----------
__global__ void scanAB(u32* __restrict__ HG, u32* __restrict__ blockSums,
                       u32* __restrict__ SB, u32* __restrict__ ticket, int n) {
    __shared__ u32 ts[256];
    __shared__ int isLast;
    const int ITEMS = 8;
    const int tid = threadIdx.x;
    int base = blockIdx.x * 2048 + tid * ITEMS;
    u32 v[ITEMS];
    u32 sum = 0;
#pragma unroll
    for (int i = 0; i < ITEMS; ++i) {
        int idx = base + i;
        v[i] = (idx < n) ? HG[idx] : 0;
        sum += v[i];
    }
    ts[tid] = sum;
    __syncthreads();
    u32 incl = sum;
    for (int d = 1; d < 256; d <<= 1) {
        u32 y = 0;
        if (tid >= d) y = ts[tid - d];
        __syncthreads();
        incl += y;
        ts[tid] = incl;
        __syncthreads();
    }
    u32 run = incl - sum;
#pragma unroll
    for (int i = 0; i < ITEMS; ++i) {
        int idx = base + i;
        if (idx < n) HG[idx] = run;
        run += v[i];
    }
    if (tid == 255) {
        atomicExch(&blockSums[blockIdx.x], incl);
        __threadfence();
        u32 t = atomicAdd(&ticket[0], 1u);
        isLast = (t == gridDim.x - 1);
    }
    __syncthreads();
    if (!isLast) return;
    const int nb = gridDim.x;
    u32 bv = (tid < nb) ? atomicAdd(&blockSums[tid], 0u) : 0;
    ts[tid] = bv;
    __syncthreads();
    u32 bincl = bv;
    for (int d = 1; d < 256; d <<= 1) {
        u32 y = 0;
        if (tid >= d) y = ts[tid - d];
        __syncthreads();
        bincl += y;
        ts[tid] = bincl;
        __syncthreads();
    }
    if (tid < nb) SB[tid] = bincl - bv;
}

// ---------- pass 1b: rank via LDS atomics; write packed (dst&511)<<17|src ----------
__global__ void __launch_bounds__(256) p1_scatter(const void* __restrict__ edge,
                                                  const int* __restrict__ flag,
                                                  const u32* __restrict__ HG,
                                                  const u32* __restrict__ SB,
                                                  u32* __restrict__ P, int E, int n, int nb1) {
    __shared__ u32 base[256];
    __shared__ u32 cur[256];
    const int tid = threadIdx.x;
    cur[tid] = 0;
    for (int b = tid; b < nb1; b += 256) {
        int i = b * NBLK1 + blockIdx.x;
        base[b] = HG[i] + SB[i >> 11];
    }
    __syncthreads();
    const int w64 = flag[0];
    const int chunk = (E + NBLK1 - 1) / NBLK1;
    const int s = blockIdx.x * chunk;
    const int e = min(s + chunk, E);
    for (int i = s + tid; i < e; i += 256) {
        int d = gidx(edge, (long long)E + i, w64);
        if ((unsigned)d >= (unsigned)n) d = 0;
        int sv = gidx(edge, i, w64);
        if ((unsigned)sv >= (unsigned)n) sv = 0;
        const int b1 = d >> 9;
        u32 r = atomicAdd(&cur[b1], 1);
        P[base[b1] + r] = (u32)sv | ((u32)(d & 511) << 17);
    }
}

// ---------- pass 2: per coarse bucket — fine hist(512), LDS scan, offs + final ss ----------
__global__ void __launch_bounds__(256) p2_kernel(const u32* __restrict__ P,
                                                 const u32* __restrict__ HG,
                                                 const u32* __restrict__ SB,
                                                 u32* __restrict__ offs,
                                                 int* __restrict__ ss,
                                                 float* __restrict__ pool,
                                                 int E, int n, int nb1) {
    __shared__ u32 h2[512];
    __shared__ u32 ts[256];
    const int tid = threadIdx.x;
    const int b = blockIdx.x;
    if (b == 0)
        for (int i = tid; i < 4096; i += 256) pool[i] = 0.f;
    const int i0 = b * NBLK1;
    const int bs = (int)(HG[i0] + SB[i0 >> 11]);
    int be;
    if (b + 1 < nb1) {
        const int i1 = (b + 1) * NBLK1;
        be = (int)(HG[i1] + SB[i1 >> 11]);
    } else be = E;
    h2[tid] = 0;
    h2[tid + 256] = 0;
    __syncthreads();
    for (int i = bs + tid; i < be; i += 256) atomicAdd(&h2[(P[i] >> 17) & 511], 1);
    __syncthreads();
    u32 v0 = h2[2 * tid], v1 = h2[2 * tid + 1];
    u32 sum = v0 + v1;
    ts[tid] = sum;
    __syncthreads();
    u32 incl = sum;
    for (int d = 1; d < 256; d <<= 1) {
        u32 y = 0;
        if (tid >= d) y = ts[tid - d];
        __syncthreads();
        incl += y;
        ts[tid] = incl;
        __syncthreads();
    }
    u32 run = incl - sum;
    h2[2 * tid] = run;
    h2[2 * tid + 1] = run + v0;
    const int node0 = b * 512 + 2 * tid;
    if (node0 < n) offs[node0] = bs + run;
    if (node0 + 1 < n) offs[node0 + 1] = bs + run + v0;
    if (b == 0 && tid == 0) offs[n] = (u32)E;
    __syncthreads();
    for (int i = bs + tid; i < be; i += 256) {
        u32 p = P[i];
        u32 r = atomicAdd(&h2[(p >> 17) & 511], 1);
        ss[bs + r] = (int)(p & 0x1FFFFu);
    }
}

// ---------- MFMA lift (layers 2,3): Z = X@Wl (f16), R = X@Wr + b (f16) ----------
__global__ void __launch_bounds__(256) mm_mfma_kernel(const u16* __restrict__ X,
                                                      const float* __restrict__ Wl,
                                                      const float* __restrict__ Wr,
                                                      const float* __restrict__ Bv,
                                                      u16* __restrict__ Z,
                                                      u16* __restrict__ R, int n) {
    const int lane = threadIdx.x & 63;
    const int quad = lane >> 4;
    const int m16 = lane & 15;
    f16x8 bl[2][4], br[2][4];
#pragma unroll
    for (int kh = 0; kh < 2; ++kh)
#pragma unroll
        for (int t = 0; t < 4; ++t)
#pragma unroll
            for (int j = 0; j < 8; ++j) {
                int k = kh * 32 + quad * 8 + j;
                int c = t * 16 + m16;
                bl[kh][t][j] = (_Float16)Wl[k * 64 + c];
                br[kh][t][j] = (_Float16)Wr[k * 64 + c];
            }
    float bias_t[4];
#pragma unroll
    for (int t = 0; t < 4; ++t) bias_t[t] = Bv[t * 16 + m16];

    const int ntiles = (n + 15) >> 4;
    const int nwaves = gridDim.x * 4;
    for (int tile = blockIdx.x * 4 + (threadIdx.x >> 6); tile < ntiles; tile += nwaves) {
        const int nodeBase = tile << 4;
        int nodeA = nodeBase + m16;
        if (nodeA >= n) nodeA = n - 1;
        const _Float16* xp = (const _Float16*)X + (size_t)nodeA * 64;
        f16x8 a[2];
#pragma unroll
        for (int kh = 0; kh < 2; ++kh)
            a[kh] = *(const f16x8*)(xp + kh * 32 + quad * 8);
        f32x4 cl[4], cr[4];
#pragma unroll
        for (int t = 0; t < 4; ++t) {
            f32x4 c0 = {0.f, 0.f, 0.f, 0.f};
            c0 = __builtin_amdgcn_mfma_f32_16x16x32_f16(a[0], bl[0][t], c0, 0, 0, 0);
            c0 = __builtin_amdgcn_mfma_f32_16x16x32_f16(a[1], bl[1][t], c0, 0, 0, 0);
            cl[t] = c0;
            f32x4 c1 = {0.f, 0.f, 0.f, 0.f};
            c1 = __builtin_amdgcn_mfma_f32_16x16x32_f16(a[0], br[0][t], c1, 0, 0, 0);
            c1 = __builtin_amdgcn_mfma_f32_16x16x32_f16(a[1], br[1][t], c1, 0, 0, 0);
            cr[t] = c1;
        }
#pragma unroll
        for (int rg = 0; rg < 4; ++rg) {
            const int node = nodeBase + quad * 4 + rg;
            if (node < n) {
#pragma unroll
                for (int t = 0; t < 4; ++t) {
                    const int c = t * 16 + m16;
                    Z[(size_t)node * 64 + c] = f2h(cl[t][rg]);
                    R[(size_t)node * 64 + c] = f2h(cr[t][rg] + bias_t[t]);
                }
            }
        }
    }
}

// ---------- aggregation: oct layout — uint4 gathers, 8 rows per wave-load instruction ----
__global__ void __launch_bounds__(256) agg_kernel(const u16* __restrict__ Zin,
                                                  const u16* __restrict__ Rin,
                                                  const u32* __restrict__ offs,
                                                  const int* __restrict__ ss,
                                                  u16* __restrict__ Hout, int n) {
    const int lane = threadIdx.x & 63;
    const int oct = lane >> 3;     // octet handles rows j == oct (mod 8)
    const int sub = lane & 7;      // 16-byte chunk within a 128 B row
    const uint4* Z16 = (const uint4*)Zin;   // row = 8 uint4
    const int node = (blockIdx.x << 2) | (threadIdx.x >> 6);
    if (node >= n) return;
    const int off = (int)offs[node], end = (int)offs[node + 1];
    const int deg = end - off;
    const __half2 zero2 = __float2half2_rn(0.f);
    const __half2 one2 = __float2half2_rn(1.f);
    __half2 a0 = zero2, a1 = zero2, a2 = zero2, a3 = zero2;
    __half2 b0 = zero2, b1 = zero2, b2 = zero2, b3 = zero2;
    for (int base = off; base < end; base += 64) {
        const int cnt = min(64, end - base);
        const int idx = ss[base + (lane < cnt ? lane : cnt - 1)];
        int p = 0;
        for (; p + 16 <= cnt; p += 16) {
            int s0 = __shfl(idx, p + oct, 64);
            int s1 = __shfl(idx, p + 8 + oct, 64);
            uint4 u0 = Z16[(size_t)s0 * 8 + sub];
            uint4 u1 = Z16[(size_t)s1 * 8 + sub];
            a0 = __hadd2(a0, *(const __half2*)&u0.x);
            a1 = __hadd2(a1, *(const __half2*)&u0.y);
            a2 = __hadd2(a2, *(const __half2*)&u0.z);
            a3 = __hadd2(a3, *(const __half2*)&u0.w);
            b0 = __hadd2(b0, *(const __half2*)&u1.x);
            b1 = __hadd2(b1, *(const __half2*)&u1.y);
            b2 = __hadd2(b2, *(const __half2*)&u1.z);
            b3 = __hadd2(b3, *(const __half2*)&u1.w);
        }
        const int rem = cnt - p;   // 0..15
        if (rem) {
            int j = p + oct;
            int s0 = __shfl(idx, j < cnt ? j : cnt - 1, 64);
            uint4 u0 = Z16[(size_t)s0 * 8 + sub];
            __half2 m0 = (j < cnt) ? one2 : zero2;
            a0 = __hfma2(*(const __half2*)&u0.x, m0, a0);
            a1 = __hfma2(*(const __half2*)&u0.y, m0, a1);
            a2 = __hfma2(*(const __half2*)&u0.z, m0, a2);
            a3 = __hfma2(*(const __half2*)&u0.w, m0, a3);
            if (rem > 8) {
                int j1 = p + 8 + oct;
                int s1 = __shfl(idx, j1 < cnt ? j1 : cnt - 1, 64);
                uint4 u1 = Z16[(size_t)s1 * 8 + sub];
                __half2 m1 = (j1 < cnt) ? one2 : zero2;
                b0 = __hfma2(*(const __half2*)&u1.x, m1, b0);
                b1 = __hfma2(*(const __half2*)&u1.y, m1, b1);
                b2 = __hfma2(*(const __half2*)&u1.z, m1, b2);
                b3 = __hfma2(*(const __half2*)&u1.w, m1, b3);
            }
        }
    }
    a0 = __hadd2(a0, b0); a1 = __hadd2(a1, b1);
    a2 = __hadd2(a2, b2); a3 = __hadd2(a3, b3);
    a0 = __hadd2(a0, sx(a0, 8));  a1 = __hadd2(a1, sx(a1, 8));
    a2 = __hadd2(a2, sx(a2, 8));  a3 = __hadd2(a3, sx(a3, 8));
    a0 = __hadd2(a0, sx(a0, 16)); a1 = __hadd2(a1, sx(a1, 16));
    a2 = __hadd2(a2, sx(a2, 16)); a3 = __hadd2(a3, sx(a3, 16));
    a0 = __hadd2(a0, sx(a0, 32)); a1 = __hadd2(a1, sx(a1, 32));
    a2 = __hadd2(a2, sx(a2, 32)); a3 = __hadd2(a3, sx(a3, 32));
    if (oct == 0) {
        const uint4* R16 = (const uint4*)Rin;
        uint4 rr = R16[(size_t)node * 8 + sub];
        const float rd = deg > 0 ? 1.f / (float)deg : 0.f;
        float2 sA = __half22float2(a0), rA = __half22float2(*(const __half2*)&rr.x);
        float2 sB = __half22float2(a1), rB = __half22float2(*(const __half2*)&rr.y);
        float2 sC = __half22float2(a2), rC = __half22float2(*(const __half2*)&rr.z);
        float2 sD = __half22float2(a3), rD = __half22float2(*(const __half2*)&rr.w);
        uint4 outp;
        outp.x = packh2(fmaxf(fmaf(sA.x, rd, rA.x), 0.f), fmaxf(fmaf(sA.y, rd, rA.y), 0.f));
        outp.y = packh2(fmaxf(fmaf(sB.x, rd, rB.x), 0.f), fmaxf(fmaf(sB.y, rd, rB.y), 0.f));
        outp.z = packh2(fmaxf(fmaf(sC.x, rd, rC.x), 0.f), fmaxf(fmaf(sC.y, rd, rC.y), 0.f));
        outp.w = packh2(fmaxf(fmaf(sD.x, rd, rD.x), 0.f), fmaxf(fmaf(sD.y, rd, rD.y), 0.f));
        *(uint4*)(((u32*)Hout) + (size_t)node * 32 + 4 * sub) = outp;
    }
}

// ---------- pool + head fused (single-ticket last block runs head; no spin) ----------
__global__ void __launch_bounds__(256) pool_head_kernel(
        const u16* __restrict__ H, const void* __restrict__ batch,
        const int* __restrict__ flag, float* __restrict__ pool,
        u32* __restrict__ ticket,
        const float* __restrict__ Wc1, const float* __restrict__ bc1,
        const float* __restrict__ Wc2, const float* __restrict__ bc2,
        float* __restrict__ out, int n) {
    const int tid = threadIdx.x;
    const int lane = tid & 63, wave = tid >> 6;
    const int w64 = flag[0];
    // ---- pool phase: this block covers rows [blockIdx*256, +256) ----
    {
        int start = (blockIdx.x * 4 + wave) * 64;
        int end = min(start + 64, n);
        if (start < end) {
            float acc = 0.f;
            int cur = gidx(batch, start, w64) & 63;
            for (int i = start; i < end; ++i) {
                int g = gidx(batch, i, w64) & 63;
                if (g != cur) {
                    atomicAdd(&pool[cur * 64 + lane], acc);
                    acc = 0.f;
                    cur = g;
                }
                acc += __half2float(__ushort_as_half(H[(size_t)i * 64 + lane]));
            }
            atomicAdd(&pool[cur * 64 + lane], acc);
        }
    }
    __threadfence();
    __syncthreads();
    __shared__ int isLast;
    if (tid == 0) isLast = (atomicAdd(&ticket[1], 1u) == (u32)(gridDim.x - 1));
    __syncthreads();
    if (!isLast) return;
    __threadfence();
    // ---- head phase (single block; others' pool adds ordered by fence+ticket) ----
    __shared__ float gm[64 * 64];
    __shared__ float am[64 * 32];
    __shared__ int cnts[64];
    if (tid < 64) {
        int lo = 0, hi = n;
        while (lo < hi) { int mid = (lo + hi) >> 1; if (gidx(batch, mid, w64) < tid) lo = mid + 1; else hi = mid; }
        int lo2 = 0, hi2 = n;
        int v2 = tid + 1;
        while (lo2 < hi2) { int mid = (lo2 + hi2) >> 1; if (gidx(batch, mid, w64) < v2) lo2 = mid + 1; else hi2 = mid; }
        cnts[tid] = lo2 - lo;
    }
    __syncthreads();
    for (int i = tid; i < 4096; i += 256) {
        int g = i >> 6;
        float c = (float)(cnts[g] > 0 ? cnts[g] : 1);
        gm[i] = atomicAdd(&pool[i], 0.f) / c;   // atomic read: device-coherent
    }
    __syncthreads();
    for (int i = tid; i < 64 * 32; i += 256) {
        int g = i >> 5, j = i & 31;
        float acc = bc1[j];
        for (int k = 0; k < 64; ++k) acc += gm[g * 64 + k] * Wc1[k * 32 + j];
        am[i] = acc > 0.f ? acc : 0.f;
    }
    __syncthreads();
    if (tid < 128) {
        int g = tid >> 1, o = tid & 1;
        float acc = bc2[o];
        for (int j = 0; j < 32; ++j) acc += am[g * 32 + j] * Wc2[j * 2 + o];
        out[tid] = acc;
    }
}

extern "C" void kernel_launch(void* const* d_in, const int* in_sizes, int n_in,
                              void* d_out, int out_size, void* d_ws, size_t ws_size,
                              hipStream_t stream) {
    const float* x   = (const float*)d_in[0];
    const void* edge = d_in[1];     // int32 or int64, auto-detected
    const void* batch = d_in[2];
    const float* W1l = (const float*)d_in[3];
    const float* b1  = (const float*)d_in[4];
    const float* W1r = (const float*)d_in[5];
    const float* W2l = (const float*)d_in[6];
    const float* b2  = (const float*)d_in[7];
    const float* W2r = (const float*)d_in[8];
    const float* W3l = (const float*)d_in[9];
    const float* b3  = (const float*)d_in[10];
    const float* W3r = (const float*)d_in[11];
    const float* Wc1 = (const float*)d_in[12];
    const float* bc1 = (const float*)d_in[13];
    const float* Wc2 = (const float*)d_in[14];
    const float* bc2 = (const float*)d_in[15];

    const int n = in_sizes[0] / 64;   // 100000
    const int E = in_sizes[1] / 2;    // 1600000
    const int nb1 = (n + 511) >> 9;   // 196 coarse buckets (requires <= 256)
    const int NS = nb1 * NBLK1;       // scanned histogram length
    const int npool = (n + 255) >> 8; // 391

    char* w = (char*)d_ws;
    size_t o = 0;
    auto take = [&](size_t bytes) -> void* {
        void* p = w + o;
        o = (o + bytes + 511) & ~(size_t)511;
        return p;
    };
    int* flag      = (int*)take(sizeof(int));
    u32* ticket    = (u32*)take(2 * sizeof(u32));
    u32* offs      = (u32*)take((size_t)(n + 1) * sizeof(u32));
    u32* HG        = (u32*)take((size_t)(NS + 1) * sizeof(u32));
    u32* blockSums = (u32*)take(256 * sizeof(u32));
    u32* SB        = (u32*)take(256 * sizeof(u32));
    u32* P         = (u32*)take((size_t)E * sizeof(u32));
    int* ss        = (int*)take((size_t)E * sizeof(int));
    u16* Z         = (u16*)take((size_t)n * 64 * sizeof(u16));
    u16* R         = (u16*)take((size_t)n * 64 * sizeof(u16));
    u16* HA        = (u16*)take((size_t)n * 64 * sizeof(u16));
    u16* HB        = (u16*)take((size_t)n * 64 * sizeof(u16));
    float* pool    = (float*)take(64 * 64 * sizeof(float));

    // CSR hist + layer-1 lift in one launch (also writes flag/tickets)
    fused_hist_mm1<<<NBLK1 + MMBLK, 256, 0, stream>>>(edge, flag, ticket, HG, E, n, nb1,
                                                      x, W1l, W1r, b1, Z, R);
    const int nbScan = (NS + 2047) / 2048;
    scanAB<<<nbScan, 256, 0, stream>>>(HG, blockSums, SB, ticket, NS);
    p1_scatter<<<NBLK1, 256, 0, stream>>>(edge, flag, HG, SB, P, E, n, nb1);
    p2_kernel<<<nb1, 256, 0, stream>>>(P, HG, SB, offs, ss, pool, E, n, nb1);

    const int nodeBlocks = (n + 3) / 4;
    agg_kernel<<<nodeBlocks, 256, 0, stream>>>(Z, R, offs, ss, HA, n);
    mm_mfma_kernel<<<MMBLK, 256, 0, stream>>>(HA, W2l, W2r, b2, Z, R, n);
    agg_kernel<<<nodeBlocks, 256, 0, stream>>>(Z, R, offs, ss, HB, n);
    mm_mfma_kernel<<<MMBLK, 256, 0, stream>>>(HB, W3l, W3r, b3, Z, R, n);
    agg_kernel<<<nodeBlocks, 256, 0, stream>>>(Z, R, offs, ss, HA, n);

    pool_head_kernel<<<npool, 256, 0, stream>>>(HA, batch, flag, pool, ticket,
                                                Wc1, bc1, Wc2, bc2,
                                                (float*)d_out, n);
}

// Round 16
// 333.714 us; speedup vs baseline: 8.5047x; 1.0903x over previous
//
#include <hip/hip_runtime.h>
#include <hip/hip_bf16.h>
#include <hip/hip_fp16.h>

typedef unsigned int u32;
typedef unsigned short u16;
typedef _Float16 f16x8 __attribute__((ext_vector_type(8)));
typedef float f32x4 __attribute__((ext_vector_type(4)));

#define NBLK1 512   // pass-1 blocks (edge chunks)
#define MMBLK 256   // mm blocks (1024 waves, ~6 tiles/wave: weight-frag setup amortized)

// ---------- fp16 pack/unpack ----------
__device__ __forceinline__ u16 f2h(float f) { return __half_as_ushort(__float2half(f)); }
__device__ __forceinline__ u32 packh2(float a, float b) {
    return (u32)f2h(a) | ((u32)f2h(b) << 16);
}
__device__ __forceinline__ __half2 sx(__half2 v, int m) {
    int iv = __shfl_xor(*(int*)&v, m, 64);
    return *(__half2*)&iv;
}

// ---------- int-width-agnostic index load (w64=1 -> int64 data on device) ----------
__device__ __forceinline__ int gidx(const void* p, long long i, int w64) {
    if (w64) return (int)((const long long*)p)[i];
    return ((const int*)p)[i];
}

// per-block int64 detection (probe odd words; int32 data -> some nonzero, int64 -> all zero)
__device__ __forceinline__ int detect_w64(const int* edge_words, int E, int tid, int* sh) {
    if (tid == 0) *sh = 0;
    __syncthreads();
    const long long totalWords = 2LL * E;
    const long long step = totalWords / 256;
    long long w = ((long long)tid * step) | 1;
    int nz = (w < totalWords) ? edge_words[w] : 0;
    if (nz) atomicOr(sh, 1);
    __syncthreads();
    return (*sh) ? 0 : 1;
}

// ---------- fused: p1_hist (blocks < NBLK1) + layer-1 MFMA lift (rest) ----------
__global__ void __launch_bounds__(256) fused_hist_mm1(
        const void* __restrict__ edge, int* __restrict__ flag, u32* __restrict__ ticket,
        u32* __restrict__ HG, int E, int n, int nb1,
        const float* __restrict__ X, const float* __restrict__ Wl,
        const float* __restrict__ Wr, const float* __restrict__ Bv,
        u16* __restrict__ Z, u16* __restrict__ R) {
    if (blockIdx.x < NBLK1) {
        __shared__ u32 h[256];
        __shared__ int shnz;
        const int tid = threadIdx.x;
        h[tid] = 0;
        const int w64 = detect_w64((const int*)edge, E, tid, &shnz);
        if (blockIdx.x == 0 && tid == 0) { flag[0] = w64; ticket[0] = 0; }
        __syncthreads();
        const int chunk = (E + NBLK1 - 1) / NBLK1;
        const int s = blockIdx.x * chunk;
        const int e = min(s + chunk, E);
        for (int i = s + tid; i < e; i += 256) {
            int d = gidx(edge, (long long)E + i, w64);
            if ((unsigned)d >= (unsigned)n) d = 0;
            atomicAdd(&h[d >> 9], 1);
        }
        __syncthreads();
        for (int b = tid; b < nb1; b += 256) HG[b * NBLK1 + blockIdx.x] = h[b];
        return;
    }
    const int lane = threadIdx.x & 63;
    const int quad = lane >> 4;
    const int m16 = lane & 15;
    f16x8 bl[2][4], br[2][4];
#pragma unroll
    for (int kh = 0; kh < 2; ++kh)
#pragma unroll
        for (int t = 0; t < 4; ++t)
#pragma unroll
            for (int j = 0; j < 8; ++j) {
                int k = kh * 32 + quad * 8 + j;
                int c = t * 16 + m16;
                bl[kh][t][j] = (_Float16)Wl[k * 64 + c];
                br[kh][t][j] = (_Float16)Wr[k * 64 + c];
            }
    float bias_t[4];
#pragma unroll
    for (int t = 0; t < 4; ++t) bias_t[t] = Bv[t * 16 + m16];

    const int ntiles = (n + 15) >> 4;
    const int nwaves = (gridDim.x - NBLK1) * 4;
    for (int tile = (blockIdx.x - NBLK1) * 4 + (threadIdx.x >> 6); tile < ntiles; tile += nwaves) {
        const int nodeBase = tile << 4;
        int nodeA = nodeBase + m16;
        if (nodeA >= n) nodeA = n - 1;
        f16x8 a[2];
#pragma unroll
        for (int kh = 0; kh < 2; ++kh) {
            const float4* p = (const float4*)(X + (size_t)nodeA * 64 + kh * 32 + quad * 8);
            float4 x0 = p[0], x1 = p[1];
            a[kh][0] = (_Float16)x0.x; a[kh][1] = (_Float16)x0.y;
            a[kh][2] = (_Float16)x0.z; a[kh][3] = (_Float16)x0.w;
            a[kh][4] = (_Float16)x1.x; a[kh][5] = (_Float16)x1.y;
            a[kh][6] = (_Float16)x1.z; a[kh][7] = (_Float16)x1.w;
        }
        f32x4 cl[4], cr[4];
#pragma unroll
        for (int t = 0; t < 4; ++t) {
            f32x4 c0 = {0.f, 0.f, 0.f, 0.f};
            c0 = __builtin_amdgcn_mfma_f32_16x16x32_f16(a[0], bl[0][t], c0, 0, 0, 0);
            c0 = __builtin_amdgcn_mfma_f32_16x16x32_f16(a[1], bl[1][t], c0, 0, 0, 0);
            cl[t] = c0;
            f32x4 c1 = {0.f, 0.f, 0.f, 0.f};
            c1 = __builtin_amdgcn_mfma_f32_16x16x32_f16(a[0], br[0][t], c1, 0, 0, 0);
            c1 = __builtin_amdgcn_mfma_f32_16x16x32_f16(a[1], br[1][t], c1, 0, 0, 0);
            cr[t] = c1;
        }
#pragma unroll
        for (int rg = 0; rg < 4; ++rg) {
            const int node = nodeBase + quad * 4 + rg;
            if (node < n) {
#pragma unroll
                for (int t = 0; t < 4; ++t) {
                    const int c = t * 16 + m16;
                    Z[(size_t)node * 64 + c] = f2h(cl[t][rg]);
                    R[(size_t)node * 64 + c] = f2h(cr[t][rg] + bias_t[t]);
                }
            }
        }
    }
}

// ---------- scanA with fused scanB (ticketed last block — single waiter, no spin) ----------
__global__ void scanAB(u32* __restrict__ HG, u32* __restrict__ blockSums,
                       u32* __restrict__ SB, u32* __restrict__ ticket, int n) {
    __shared__ u32 ts[256];
    __shared__ int isLast;
    const int ITEMS = 8;
    const int tid = threadIdx.x;
    int base = blockIdx.x * 2048 + tid * ITEMS;
    u32 v[ITEMS];
    u32 sum = 0;
#pragma unroll
    for (int i = 0; i < ITEMS; ++i) {
        int idx = base + i;
        v[i] = (idx < n) ? HG[idx] : 0;
        sum += v[i];
    }
    ts[tid] = sum;
    __syncthreads();
    u32 incl = sum;
    for (int d = 1; d < 256; d <<= 1) {
        u32 y = 0;
        if (tid >= d) y = ts[tid - d];
        __syncthreads();
        incl += y;
        ts[tid] = incl;
        __syncthreads();
    }
    u32 run = incl - sum;
#pragma unroll
    for (int i = 0; i < ITEMS; ++i) {
        int idx = base + i;
        if (idx < n) HG[idx] = run;
        run += v[i];
    }
    if (tid == 255) {
        atomicExch(&blockSums[blockIdx.x], incl);
        __threadfence();
        u32 t = atomicAdd(&ticket[0], 1u);
        isLast = (t == gridDim.x - 1);
    }
    __syncthreads();
    if (!isLast) return;
    const int nb = gridDim.x;
    u32 bv = (tid < nb) ? atomicAdd(&blockSums[tid], 0u) : 0;
    ts[tid] = bv;
    __syncthreads();
    u32 bincl = bv;
    for (int d = 1; d < 256; d <<= 1) {
        u32 y = 0;
        if (tid >= d) y = ts[tid - d];
        __syncthreads();
        bincl += y;
        ts[tid] = bincl;
        __syncthreads();
    }
    if (tid < nb) SB[tid] = bincl - bv;
}

// ---------- pass 1b: rank via LDS atomics; write packed (dst&511)<<17|src ----------
__global__ void __launch_bounds__(256) p1_scatter(const void* __restrict__ edge,
                                                  const int* __restrict__ flag,
                                                  const u32* __restrict__ HG,
                                                  const u32* __restrict__ SB,
                                                  u32* __restrict__ P, int E, int n, int nb1) {
    __shared__ u32 base[256];
    __shared__ u32 cur[256];
    const int tid = threadIdx.x;
    cur[tid] = 0;
    for (int b = tid; b < nb1; b += 256) {
        int i = b * NBLK1 + blockIdx.x;
        base[b] = HG[i] + SB[i >> 11];
    }
    __syncthreads();
    const int w64 = flag[0];
    const int chunk = (E + NBLK1 - 1) / NBLK1;
    const int s = blockIdx.x * chunk;
    const int e = min(s + chunk, E);
    for (int i = s + tid; i < e; i += 256) {
        int d = gidx(edge, (long long)E + i, w64);
        if ((unsigned)d >= (unsigned)n) d = 0;
        int sv = gidx(edge, i, w64);
        if ((unsigned)sv >= (unsigned)n) sv = 0;
        const int b1 = d >> 9;
        u32 r = atomicAdd(&cur[b1], 1);
        P[base[b1] + r] = (u32)sv | ((u32)(d & 511) << 17);
    }
}

// ---------- pass 2: per coarse bucket — fine hist(512), LDS scan, offs + final ss ----------
__global__ void __launch_bounds__(256) p2_kernel(const u32* __restrict__ P,
                                                 const u32* __restrict__ HG,
                                                 const u32* __restrict__ SB,
                                                 u32* __restrict__ offs,
                                                 int* __restrict__ ss,
                                                 float* __restrict__ pool,
                                                 int E, int n, int nb1) {
    __shared__ u32 h2[512];
    __shared__ u32 ts[256];
    const int tid = threadIdx.x;
    const int b = blockIdx.x;
    if (b == 0)
        for (int i = tid; i < 4096; i += 256) pool[i] = 0.f;
    const int i0 = b * NBLK1;
    const int bs = (int)(HG[i0] + SB[i0 >> 11]);
    int be;
    if (b + 1 < nb1) {
        const int i1 = (b + 1) * NBLK1;
        be = (int)(HG[i1] + SB[i1 >> 11]);
    } else be = E;
    h2[tid] = 0;
    h2[tid + 256] = 0;
    __syncthreads();
    for (int i = bs + tid; i < be; i += 256) atomicAdd(&h2[(P[i] >> 17) & 511], 1);
    __syncthreads();
    u32 v0 = h2[2 * tid], v1 = h2[2 * tid + 1];
    u32 sum = v0 + v1;
    ts[tid] = sum;
    __syncthreads();
    u32 incl = sum;
    for (int d = 1; d < 256; d <<= 1) {
        u32 y = 0;
        if (tid >= d) y = ts[tid - d];
        __syncthreads();
        incl += y;
        ts[tid] = incl;
        __syncthreads();
    }
    u32 run = incl - sum;
    h2[2 * tid] = run;
    h2[2 * tid + 1] = run + v0;
    const int node0 = b * 512 + 2 * tid;
    if (node0 < n) offs[node0] = bs + run;
    if (node0 + 1 < n) offs[node0 + 1] = bs + run + v0;
    if (b == 0 && tid == 0) offs[n] = (u32)E;
    __syncthreads();
    for (int i = bs + tid; i < be; i += 256) {
        u32 p = P[i];
        u32 r = atomicAdd(&h2[(p >> 17) & 511], 1);
        ss[bs + r] = (int)(p & 0x1FFFFu);
    }
}

// ---------- MFMA lift (layers 2,3): Z = X@Wl (f16), R = X@Wr + b (f16) ----------
__global__ void __launch_bounds__(256) mm_mfma_kernel(const u16* __restrict__ X,
                                                      const float* __restrict__ Wl,
                                                      const float* __restrict__ Wr,
                                                      const float* __restrict__ Bv,
                                                      u16* __restrict__ Z,
                                                      u16* __restrict__ R, int n) {
    const int lane = threadIdx.x & 63;
    const int quad = lane >> 4;
    const int m16 = lane & 15;
    f16x8 bl[2][4], br[2][4];
#pragma unroll
    for (int kh = 0; kh < 2; ++kh)
#pragma unroll
        for (int t = 0; t < 4; ++t)
#pragma unroll
            for (int j = 0; j < 8; ++j) {
                int k = kh * 32 + quad * 8 + j;
                int c = t * 16 + m16;
                bl[kh][t][j] = (_Float16)Wl[k * 64 + c];
                br[kh][t][j] = (_Float16)Wr[k * 64 + c];
            }
    float bias_t[4];
#pragma unroll
    for (int t = 0; t < 4; ++t) bias_t[t] = Bv[t * 16 + m16];

    const int ntiles = (n + 15) >> 4;
    const int nwaves = gridDim.x * 4;
    for (int tile = blockIdx.x * 4 + (threadIdx.x >> 6); tile < ntiles; tile += nwaves) {
        const int nodeBase = tile << 4;
        int nodeA = nodeBase + m16;
        if (nodeA >= n) nodeA = n - 1;
        const _Float16* xp = (const _Float16*)X + (size_t)nodeA * 64;
        f16x8 a[2];
#pragma unroll
        for (int kh = 0; kh < 2; ++kh)
            a[kh] = *(const f16x8*)(xp + kh * 32 + quad * 8);
        f32x4 cl[4], cr[4];
#pragma unroll
        for (int t = 0; t < 4; ++t) {
            f32x4 c0 = {0.f, 0.f, 0.f, 0.f};
            c0 = __builtin_amdgcn_mfma_f32_16x16x32_f16(a[0], bl[0][t], c0, 0, 0, 0);
            c0 = __builtin_amdgcn_mfma_f32_16x16x32_f16(a[1], bl[1][t], c0, 0, 0, 0);
            cl[t] = c0;
            f32x4 c1 = {0.f, 0.f, 0.f, 0.f};
            c1 = __builtin_amdgcn_mfma_f32_16x16x32_f16(a[0], br[0][t], c1, 0, 0, 0);
            c1 = __builtin_amdgcn_mfma_f32_16x16x32_f16(a[1], br[1][t], c1, 0, 0, 0);
            cr[t] = c1;
        }
#pragma unroll
        for (int rg = 0; rg < 4; ++rg) {
            const int node = nodeBase + quad * 4 + rg;
            if (node < n) {
#pragma unroll
                for (int t = 0; t < 4; ++t) {
                    const int c = t * 16 + m16;
                    Z[(size_t)node * 64 + c] = f2h(cl[t][rg]);
                    R[(size_t)node * 64 + c] = f2h(cr[t][rg] + bias_t[t]);
                }
            }
        }
    }
}

// ---------- aggregation: oct layout — uint4 gathers, 8 rows per wave-load instruction ----
__global__ void __launch_bounds__(256) agg_kernel(const u16* __restrict__ Zin,
                                                  const u16* __restrict__ Rin,
                                                  const u32* __restrict__ offs,
                                                  const int* __restrict__ ss,
                                                  u16* __restrict__ Hout, int n) {
    const int lane = threadIdx.x & 63;
    const int oct = lane >> 3;     // octet handles rows j == oct (mod 8)
    const int sub = lane & 7;      // 16-byte chunk within a 128 B row
    const uint4* Z16 = (const uint4*)Zin;   // row = 8 uint4
    const int node = (blockIdx.x << 2) | (threadIdx.x >> 6);
    if (node >= n) return;
    const int off = (int)offs[node], end = (int)offs[node + 1];
    const int deg = end - off;
    const __half2 zero2 = __float2half2_rn(0.f);
    const __half2 one2 = __float2half2_rn(1.f);
    __half2 a0 = zero2, a1 = zero2, a2 = zero2, a3 = zero2;
    __half2 b0 = zero2, b1 = zero2, b2 = zero2, b3 = zero2;
    for (int base = off; base < end; base += 64) {
        const int cnt = min(64, end - base);
        const int idx = ss[base + (lane < cnt ? lane : cnt - 1)];
        int p = 0;
        for (; p + 16 <= cnt; p += 16) {
            int s0 = __shfl(idx, p + oct, 64);
            int s1 = __shfl(idx, p + 8 + oct, 64);
            uint4 u0 = Z16[(size_t)s0 * 8 + sub];
            uint4 u1 = Z16[(size_t)s1 * 8 + sub];
            a0 = __hadd2(a0, *(const __half2*)&u0.x);
            a1 = __hadd2(a1, *(const __half2*)&u0.y);
            a2 = __hadd2(a2, *(const __half2*)&u0.z);
            a3 = __hadd2(a3, *(const __half2*)&u0.w);
            b0 = __hadd2(b0, *(const __half2*)&u1.x);
            b1 = __hadd2(b1, *(const __half2*)&u1.y);
            b2 = __hadd2(b2, *(const __half2*)&u1.z);
            b3 = __hadd2(b3, *(const __half2*)&u1.w);
        }
        const int rem = cnt - p;   // 0..15
        if (rem) {
            int j = p + oct;
            int s0 = __shfl(idx, j < cnt ? j : cnt - 1, 64);
            uint4 u0 = Z16[(size_t)s0 * 8 + sub];
            __half2 m0 = (j < cnt) ? one2 : zero2;
            a0 = __hfma2(*(const __half2*)&u0.x, m0, a0);
            a1 = __hfma2(*(const __half2*)&u0.y, m0, a1);
            a2 = __hfma2(*(const __half2*)&u0.z, m0, a2);
            a3 = __hfma2(*(const __half2*)&u0.w, m0, a3);
            if (rem > 8) {
                int j1 = p + 8 + oct;
                int s1 = __shfl(idx, j1 < cnt ? j1 : cnt - 1, 64);
                uint4 u1 = Z16[(size_t)s1 * 8 + sub];
                __half2 m1 = (j1 < cnt) ? one2 : zero2;
                b0 = __hfma2(*(const __half2*)&u1.x, m1, b0);
                b1 = __hfma2(*(const __half2*)&u1.y, m1, b1);
                b2 = __hfma2(*(const __half2*)&u1.z, m1, b2);
                b3 = __hfma2(*(const __half2*)&u1.w, m1, b3);
            }
        }
    }
    a0 = __hadd2(a0, b0); a1 = __hadd2(a1, b1);
    a2 = __hadd2(a2, b2); a3 = __hadd2(a3, b3);
    a0 = __hadd2(a0, sx(a0, 8));  a1 = __hadd2(a1, sx(a1, 8));
    a2 = __hadd2(a2, sx(a2, 8));  a3 = __hadd2(a3, sx(a3, 8));
    a0 = __hadd2(a0, sx(a0, 16)); a1 = __hadd2(a1, sx(a1, 16));
    a2 = __hadd2(a2, sx(a2, 16)); a3 = __hadd2(a3, sx(a3, 16));
    a0 = __hadd2(a0, sx(a0, 32)); a1 = __hadd2(a1, sx(a1, 32));
    a2 = __hadd2(a2, sx(a2, 32)); a3 = __hadd2(a3, sx(a3, 32));
    if (oct == 0) {
        const uint4* R16 = (const uint4*)Rin;
        uint4 rr = R16[(size_t)node * 8 + sub];
        const float rd = deg > 0 ? 1.f / (float)deg : 0.f;
        float2 sA = __half22float2(a0), rA = __half22float2(*(const __half2*)&rr.x);
        float2 sB = __half22float2(a1), rB = __half22float2(*(const __half2*)&rr.y);
        float2 sC = __half22float2(a2), rC = __half22float2(*(const __half2*)&rr.z);
        float2 sD = __half22float2(a3), rD = __half22float2(*(const __half2*)&rr.w);
        uint4 outp;
        outp.x = packh2(fmaxf(fmaf(sA.x, rd, rA.x), 0.f), fmaxf(fmaf(sA.y, rd, rA.y), 0.f));
        outp.y = packh2(fmaxf(fmaf(sB.x, rd, rB.x), 0.f), fmaxf(fmaf(sB.y, rd, rB.y), 0.f));
        outp.z = packh2(fmaxf(fmaf(sC.x, rd, rC.x), 0.f), fmaxf(fmaf(sC.y, rd, rC.y), 0.f));
        outp.w = packh2(fmaxf(fmaf(sD.x, rd, rD.x), 0.f), fmaxf(fmaf(sD.y, rd, rD.y), 0.f));
        *(uint4*)(((u32*)Hout) + (size_t)node * 32 + 4 * sub) = outp;
    }
}

// ---------- global mean pool (batch sorted): 64 rows/wave, no LDS ----------
__global__ void pool_kernel(const u16* __restrict__ H, const void* __restrict__ batch,
                            const int* __restrict__ flag, float* __restrict__ pool, int n) {
    const int lane = threadIdx.x & 63;
    const int wave = threadIdx.x >> 6;
    int start = (blockIdx.x * 4 + wave) * 64;
    int end = min(start + 64, n);
    if (start >= end) return;
    const int w64 = flag[0];
    float acc = 0.f;
    int cur = gidx(batch, start, w64) & 63;
    for (int i = start; i < end; ++i) {
        int g = gidx(batch, i, w64) & 63;
        if (g != cur) {
            atomicAdd(&pool[cur * 64 + lane], acc);
            acc = 0.f;
            cur = g;
        }
        acc += __half2float(__ushort_as_half(H[i * 64 + lane]));
    }
    atomicAdd(&pool[cur * 64 + lane], acc);
}

// ---------- head MLP: out = relu(g@Wc1+bc1)@Wc2 + bc2 ----------
__global__ void head_kernel(const float* __restrict__ pool, const void* __restrict__ batch,
                            const int* __restrict__ flag,
                            const float* __restrict__ Wc1, const float* __restrict__ bc1,
                            const float* __restrict__ Wc2, const float* __restrict__ bc2,
                            float* __restrict__ out, int n) {
    __shared__ float gm[64 * 64];
    __shared__ float am[64 * 32];
    __shared__ int cnts[64];
    const int tid = threadIdx.x;  // 256
    const int w64 = flag[0];
    if (tid < 64) {
        int lo = 0, hi = n;
        while (lo < hi) { int mid = (lo + hi) >> 1; if (gidx(batch, mid, w64) < tid) lo = mid + 1; else hi = mid; }
        int lo2 = 0, hi2 = n;
        int v2 = tid + 1;
        while (lo2 < hi2) { int mid = (lo2 + hi2) >> 1; if (gidx(batch, mid, w64) < v2) lo2 = mid + 1; else hi2 = mid; }
        cnts[tid] = lo2 - lo;
    }
    __syncthreads();
    for (int i = tid; i < 4096; i += 256) {
        int g = i >> 6;
        float c = (float)(cnts[g] > 0 ? cnts[g] : 1);
        gm[i] = pool[i] / c;
    }
    __syncthreads();
    for (int i = tid; i < 64 * 32; i += 256) {
        int g = i >> 5, j = i & 31;
        float acc = bc1[j];
        for (int k = 0; k < 64; ++k) acc += gm[g * 64 + k] * Wc1[k * 32 + j];
        am[i] = acc > 0.f ? acc : 0.f;
    }
    __syncthreads();
    if (tid < 128) {
        int g = tid >> 1, o = tid & 1;
        float acc = bc2[o];
        for (int j = 0; j < 32; ++j) acc += am[g * 32 + j] * Wc2[j * 2 + o];
        out[tid] = acc;
    }
}

extern "C" void kernel_launch(void* const* d_in, const int* in_sizes, int n_in,
                              void* d_out, int out_size, void* d_ws, size_t ws_size,
                              hipStream_t stream) {
    const float* x   = (const float*)d_in[0];
    const void* edge = d_in[1];     // int32 or int64, auto-detected
    const void* batch = d_in[2];
    const float* W1l = (const float*)d_in[3];
    const float* b1  = (const float*)d_in[4];
    const float* W1r = (const float*)d_in[5];
    const float* W2l = (const float*)d_in[6];
    const float* b2  = (const float*)d_in[7];
    const float* W2r = (const float*)d_in[8];
    const float* W3l = (const float*)d_in[9];
    const float* b3  = (const float*)d_in[10];
    const float* W3r = (const float*)d_in[11];
    const float* Wc1 = (const float*)d_in[12];
    const float* bc1 = (const float*)d_in[13];
    const float* Wc2 = (const float*)d_in[14];
    const float* bc2 = (const float*)d_in[15];

    const int n = in_sizes[0] / 64;   // 100000
    const int E = in_sizes[1] / 2;    // 1600000
    const int nb1 = (n + 511) >> 9;   // 196 coarse buckets (requires <= 256)
    const int NS = nb1 * NBLK1;       // scanned histogram length

    char* w = (char*)d_ws;
    size_t o = 0;
    auto take = [&](size_t bytes) -> void* {
        void* p = w + o;
        o = (o + bytes + 511) & ~(size_t)511;
        return p;
    };
    int* flag      = (int*)take(sizeof(int));
    u32* ticket    = (u32*)take(2 * sizeof(u32));
    u32* offs      = (u32*)take((size_t)(n + 1) * sizeof(u32));
    u32* HG        = (u32*)take((size_t)(NS + 1) * sizeof(u32));
    u32* blockSums = (u32*)take(256 * sizeof(u32));
    u32* SB        = (u32*)take(256 * sizeof(u32));
    u32* P         = (u32*)take((size_t)E * sizeof(u32));
    int* ss        = (int*)take((size_t)E * sizeof(int));
    u16* Z         = (u16*)take((size_t)n * 64 * sizeof(u16));
    u16* R         = (u16*)take((size_t)n * 64 * sizeof(u16));
    u16* HA        = (u16*)take((size_t)n * 64 * sizeof(u16));
    u16* HB        = (u16*)take((size_t)n * 64 * sizeof(u16));
    float* pool    = (float*)take(64 * 64 * sizeof(float));

    // CSR hist + layer-1 lift in one launch (also writes flag/ticket)
    fused_hist_mm1<<<NBLK1 + MMBLK, 256, 0, stream>>>(edge, flag, ticket, HG, E, n, nb1,
                                                      x, W1l, W1r, b1, Z, R);
    const int nbScan = (NS + 2047) / 2048;
    scanAB<<<nbScan, 256, 0, stream>>>(HG, blockSums, SB, ticket, NS);
    p1_scatter<<<NBLK1, 256, 0, stream>>>(edge, flag, HG, SB, P, E, n, nb1);
    p2_kernel<<<nb1, 256, 0, stream>>>(P, HG, SB, offs, ss, pool, E, n, nb1);

    const int nodeBlocks = (n + 3) / 4;
    agg_kernel<<<nodeBlocks, 256, 0, stream>>>(Z, R, offs, ss, HA, n);
    mm_mfma_kernel<<<MMBLK, 256, 0, stream>>>(HA, W2l, W2r, b2, Z, R, n);
    agg_kernel<<<nodeBlocks, 256, 0, stream>>>(Z, R, offs, ss, HB, n);
    mm_mfma_kernel<<<MMBLK, 256, 0, stream>>>(HB, W3l, W3r, b3, Z, R, n);
    agg_kernel<<<nodeBlocks, 256, 0, stream>>>(Z, R, offs, ss, HA, n);

    pool_kernel<<<(n + 255) / 256, 256, 0, stream>>>(HA, batch, flag, pool, n);
    head_kernel<<<1, 256, 0, stream>>>(pool, batch, flag, Wc1, bc1, Wc2, bc2,
                                       (float*)d_out, n);
}